// Round 4
// baseline (413.045 us; speedup 1.0000x reference)
//
#include <hip/hip_runtime.h>
#include <hip/hip_bf16.h>
#include <math.h>

// Problem constants
#define NBATCH 32
#define LSEQ   96
#define NN     3072
#define HID    128
#define LAT    64
#define EEMB   32

// Workspace layout (float offsets). Total ~6.35 MB.
#define OFF_H      0                          // N x 128 fp32
#define OFF_X      (OFF_H   + NN*HID)         // N x 3 (X parity buffer 0)
#define OFF_PA     (OFF_X   + NN*3)           // N x 128 fp32 (pa + be1)
#define OFF_PBH2   (OFF_PA  + NN*HID)         // N x 128 bf16 parity buf 1 (reuses old AGG space)
#define OFF_DX     (OFF_PBH2 + NN*HID)        // N x 3 (X parity buffer 1)
#define OFF_ET     (OFF_DX  + NN*3)           // 3*2*128 fp32
#define OFF_ACC    (OFF_ET  + 768)            // 8
#define OFF_NBID   (OFF_ACC + 8)              // N int
#define OFF_CUM    (OFF_NBID + NN)            // 40 int
#define OFF_PBH    (OFF_CUM + 40)             // N x 128 bf16 parity buf 0 (as 196608 floats)
#define OFF_BPE    (OFF_PBH + NN*HID/2)       // We2^T  bf16: 3*128*128 -> 24576 floats
#define OFF_BAB    (OFF_BPE + 24576)          // We1[0:256]^T bf16: 3*256*128 -> 49152
#define OFF_BH1    (OFF_BAB + 49152)          // Wh1^T bf16: 3*128*256 -> 49152
#define OFF_BH2    (OFF_BH1 + 49152)          // Wh2^T bf16: 3*128*128 -> 24576
#define OFF_BWO    (OFF_BH2 + 24576)          // Wout^T bf16: 64*128 -> 4096 floats
#define OFF_BWI1   (OFF_BWO + 4096)           // Wi1^T bf16: 128x320 -> 20480 floats
#define OFF_BWI2   (OFF_BWI1 + 20480)         // Wi2^T bf16: 128x128 -> 8192 floats
#define OFF_BWI3   (OFF_BWI2 + 8192)          // Wi3^T bf16: 128x128 -> 8192 floats
#define OFF_CNT    (OFF_BWI3 + 8192)          // 128 uint: [96] = final-election counter

typedef short bf16x8 __attribute__((ext_vector_type(8)));
typedef float f32x4  __attribute__((ext_vector_type(4)));

__device__ __forceinline__ short f2bf(float f) {
    unsigned u = __builtin_bit_cast(unsigned, f);
    unsigned r = (u + 0x7FFFu + ((u >> 16) & 1u)) >> 16;
    return (short)r;
}
__device__ __forceinline__ short2 f2bf2(float a, float b) {
    __hip_bfloat162 h = __float22bfloat162_rn(make_float2(a, b));
    short2 r;
    __builtin_memcpy(&r, &h, sizeof(r));
    return r;
}
__device__ __forceinline__ float bf2f(short s) {
    unsigned u = ((unsigned)(unsigned short)s) << 16;
    return __builtin_bit_cast(float, u);
}
__device__ __forceinline__ float silu(float z) {
    return z * __builtin_amdgcn_rcpf(1.0f + __expf(-z));
}

// --------------------- K0: prep + weight transposes (merged)
__global__ void k0_all(const float* __restrict__ edge_table, const float* __restrict__ We1,
                       const int* __restrict__ lengths, const float* __restrict__ We2,
                       const float* __restrict__ Wh1, const float* __restrict__ Wh2,
                       const float* __restrict__ Wout, const float* __restrict__ Wi1,
                       const float* __restrict__ Wi2, const float* __restrict__ Wi3,
                       float* __restrict__ ws) {
    int tid = threadIdx.x;
    if (blockIdx.x == 1472) {
        int* cum = (int*)(ws + OFF_CUM);
        int* nb  = (int*)(ws + OFF_NBID);
        float* et = ws + OFF_ET;
        if (tid == 0) {
            int s = 0;
            for (int b = 0; b < NBATCH; b++) { cum[b] = s; s += lengths[b]; }
            cum[NBATCH] = s;
        }
        if (tid < 8) ws[OFF_ACC + tid] = 0.0f;
        if (tid < 128) ((unsigned*)(ws + OFF_CNT))[tid] = 0u;
        __syncthreads();
        for (int i = tid; i < NN; i += blockDim.x) {
            int b = NBATCH - 1;
            for (int q = 0; q < NBATCH; q++) { if (i < cum[q + 1]) { b = q; break; } }
            nb[i] = b;
        }
        for (int idx = tid; idx < 3 * 2 * HID; idx += blockDim.x) {
            int c = idx & 127;
            int t = (idx >> 7) & 1;
            int l = idx >> 8;
            const float* w = We1 + (l * 289 + 257) * HID + c;
            const float* e = edge_table + t * EEMB;
            float s = 0.f;
            for (int k = 0; k < EEMB; k++) s += e[k] * w[k * HID];
            et[idx] = s;
        }
        return;
    }
    int idx = blockIdx.x * 256 + tid;   // 0 .. 376831
    short* bpe  = (short*)(ws + OFF_BPE);
    short* bab  = (short*)(ws + OFF_BAB);
    short* bh1  = (short*)(ws + OFF_BH1);
    short* bh2  = (short*)(ws + OFF_BH2);
    short* bwo  = (short*)(ws + OFF_BWO);
    short* bwi1 = (short*)(ws + OFF_BWI1);
    short* bwi2 = (short*)(ws + OFF_BWI2);
    short* bwi3 = (short*)(ws + OFF_BWI3);
    if (idx < 49152) {
        int k = idx & 127, n = (idx >> 7) & 127, l = idx >> 14;
        bpe[idx] = f2bf(We2[(l * 128 + k) * 128 + n]);
    } else if (idx < 147456) {
        int q = idx - 49152;
        int k = q & 127, n = (q >> 7) & 255, l = q >> 15;
        float v = (n < 128) ? We1[(l * 289 + k) * 128 + n]
                            : We1[(l * 289 + 128 + k) * 128 + (n - 128)];
        bab[q] = f2bf(v);
    } else if (idx < 245760) {
        int q = idx - 147456;
        int k = q & 255, n = (q >> 8) & 127, l = q >> 15;
        bh1[q] = f2bf(Wh1[(l * 256 + k) * 128 + n]);
    } else if (idx < 294912) {
        int q = idx - 245760;
        int k = q & 127, n = (q >> 7) & 127, l = q >> 14;
        bh2[q] = f2bf(Wh2[(l * 128 + k) * 128 + n]);
    } else if (idx < 303104) {
        int q = idx - 294912;
        int k = q & 127, n = q >> 7;          // n < 64
        bwo[q] = f2bf(Wout[k * 64 + n]);
    } else if (idx < 344064) {
        int q = idx - 303104;                  // [n<128][k<320]
        int n = q / 320, k = q - n * 320;
        bwi1[q] = f2bf(Wi1[k * 128 + n]);
    } else if (idx < 360448) {
        int q = idx - 344064;
        int k = q & 127, n = q >> 7;
        bwi2[q] = f2bf(Wi2[k * 128 + n]);
    } else if (idx < 376832) {
        int q = idx - 360448;
        int k = q & 127, n = q >> 7;
        bwi3[q] = f2bf(Wi3[k * 128 + n]);
    }
}

// ------------- K1s: init MLP row-split — grid (32, 6), 256 thr, 16 nodes/WG
__global__ void __launch_bounds__(256)
k1s_node_init(const float* __restrict__ H0, const float* __restrict__ X0,
              const float* __restrict__ H1, const float* __restrict__ X1,
              const float* __restrict__ cond, const float* __restrict__ tg,
              const float* __restrict__ bi1, const float* __restrict__ bi2,
              const float* __restrict__ bi3, const float* __restrict__ be1,
              const int* __restrict__ gmask, float* __restrict__ ws) {
    __shared__ short u1[16 * 136];
    __shared__ short u2[16 * 136];
    int rowbase = blockIdx.x * 96 + blockIdx.y * 16;
    int tid = threadIdx.x;
    int w = tid >> 6, lane = tid & 63;
    int quad = lane >> 4, lp = lane & 15;
    int nodeA = rowbase + lp;
    const int* nb = (const int*)(ws + OFF_NBID);
    float t = tg[nb[nodeA]];
    float u = (gmask[nodeA] != 0) ? t : 1.0f;

    if (tid < 48) {
        int node = rowbase + tid / 3, d = tid % 3;
        float tn = tg[nb[node]];
        float un = (gmask[node] != 0) ? tn : 1.0f;
        ws[OFF_X + (size_t)node * 3 + d] =
            (1.0f - un) * X0[(size_t)node * 3 + d] + un * X1[(size_t)node * 3 + d];
    }

    const short* bwi1 = (const short*)(ws + OFF_BWI1);
    const short* bwi2 = (const short*)(ws + OFF_BWI2);
    const short* bwi3 = (const short*)(ws + OFF_BWI3);
    const short* bab  = (const short*)(ws + OFF_BAB);   // l = 0

    // ---- GEMM1: K=320
    f32x4 acc[2];
    acc[0] = (f32x4){0.f, 0.f, 0.f, 0.f};
    acc[1] = (f32x4){0.f, 0.f, 0.f, 0.f};
    for (int s = 0; s < 10; s++) {
        int kb = s * 32 + quad * 8;
        float z[8];
        if (kb < 64) {
            const float* h0 = H0 + (size_t)nodeA * 64 + kb;
            const float* h1 = H1 + (size_t)nodeA * 64 + kb;
            #pragma unroll
            for (int e = 0; e < 8; e++) z[e] = (1.0f - u) * h0[e] + u * h1[e];
        } else if (kb < 192) {
            const float* cp = cond + (size_t)nodeA * 128 + (kb - 64);
            #pragma unroll
            for (int e = 0; e < 8; e++) z[e] = cp[e];
        } else if (kb < 256) {
            #pragma unroll
            for (int e = 0; e < 8; e++) {
                float c = (float)(kb - 192 + e);
                float fr = __expf(-9.2103403719761836f * c / 63.0f);
                z[e] = __sinf(t * fr);
            }
        } else {
            #pragma unroll
            for (int e = 0; e < 8; e++) {
                float c = (float)(kb - 256 + e);
                float fr = __expf(-9.2103403719761836f * c / 63.0f);
                z[e] = __cosf(t * fr);
            }
        }
        bf16x8 af;
        #pragma unroll
        for (int e = 0; e < 8; e += 2) {
            short2 p = f2bf2(z[e], z[e + 1]);
            af[e] = p.x; af[e + 1] = p.y;
        }
        #pragma unroll
        for (int i = 0; i < 2; i++) {
            int ct = 2 * w + i;
            bf16x8 bf = *(const bf16x8*)(bwi1 + (size_t)(16 * ct + lp) * 320 + kb);
            acc[i] = __builtin_amdgcn_mfma_f32_16x16x32_bf16(af, bf, acc[i], 0, 0, 0);
        }
    }
    #pragma unroll
    for (int i = 0; i < 2; i++) {
        int ch = 16 * (2 * w + i) + lp;
        float bb1 = bi1[ch];
        #pragma unroll
        for (int r = 0; r < 4; r++)
            u1[(quad * 4 + r) * 136 + ch] = f2bf(fmaxf(acc[i][r] + bb1, 0.0f));
    }
    __syncthreads();

    // ---- GEMM2: K=128
    acc[0] = (f32x4){0.f, 0.f, 0.f, 0.f};
    acc[1] = (f32x4){0.f, 0.f, 0.f, 0.f};
    #pragma unroll
    for (int s = 0; s < 4; s++) {
        int kb = s * 32 + quad * 8;
        bf16x8 af = *(const bf16x8*)(u1 + lp * 136 + kb);
        #pragma unroll
        for (int i = 0; i < 2; i++) {
            int ct = 2 * w + i;
            bf16x8 bf = *(const bf16x8*)(bwi2 + (size_t)(16 * ct + lp) * 128 + kb);
            acc[i] = __builtin_amdgcn_mfma_f32_16x16x32_bf16(af, bf, acc[i], 0, 0, 0);
        }
    }
    #pragma unroll
    for (int i = 0; i < 2; i++) {
        int ch = 16 * (2 * w + i) + lp;
        float bb2 = bi2[ch];
        #pragma unroll
        for (int r = 0; r < 4; r++)
            u2[(quad * 4 + r) * 136 + ch] = f2bf(fmaxf(acc[i][r] + bb2, 0.0f));
    }
    __syncthreads();

    // ---- GEMM3: K=128 -> h (no relu)
    acc[0] = (f32x4){0.f, 0.f, 0.f, 0.f};
    acc[1] = (f32x4){0.f, 0.f, 0.f, 0.f};
    #pragma unroll
    for (int s = 0; s < 4; s++) {
        int kb = s * 32 + quad * 8;
        bf16x8 af = *(const bf16x8*)(u2 + lp * 136 + kb);
        #pragma unroll
        for (int i = 0; i < 2; i++) {
            int ct = 2 * w + i;
            bf16x8 bf = *(const bf16x8*)(bwi3 + (size_t)(16 * ct + lp) * 128 + kb);
            acc[i] = __builtin_amdgcn_mfma_f32_16x16x32_bf16(af, bf, acc[i], 0, 0, 0);
        }
    }
    #pragma unroll
    for (int i = 0; i < 2; i++) {
        int ch = 16 * (2 * w + i) + lp;
        float bb3 = bi3[ch];
        #pragma unroll
        for (int r = 0; r < 4; r++) {
            int row = quad * 4 + r;
            float h = acc[i][r] + bb3;
            ws[OFF_H + (size_t)(rowbase + row) * 128 + ch] = h;
            u1[row * 136 + ch] = f2bf(h);
        }
    }
    __syncthreads();

    // ---- GEMM4: pa/pb layer 0, N=256 (ct4 = 4w..4w+3) -> parity buffer 0
    f32x4 acc4[4];
    #pragma unroll
    for (int i = 0; i < 4; i++) acc4[i] = (f32x4){0.f, 0.f, 0.f, 0.f};
    #pragma unroll
    for (int s = 0; s < 4; s++) {
        int kb = s * 32 + quad * 8;
        bf16x8 af = *(const bf16x8*)(u1 + lp * 136 + kb);
        #pragma unroll
        for (int i = 0; i < 4; i++) {
            int ct4 = 4 * w + i;
            bf16x8 bf = *(const bf16x8*)(bab + (size_t)(16 * ct4 + lp) * 128 + kb);
            acc4[i] = __builtin_amdgcn_mfma_f32_16x16x32_bf16(af, bf, acc4[i], 0, 0, 0);
        }
    }
    short* pbh = (short*)(ws + OFF_PBH);
    #pragma unroll
    for (int i = 0; i < 4; i++) {
        int ct4 = 4 * w + i;
        #pragma unroll
        for (int r = 0; r < 4; r++) {
            int node = rowbase + quad * 4 + r;
            if (ct4 < 8) {
                int ch = 16 * ct4 + lp;
                ws[OFF_PA + (size_t)node * 128 + ch] = acc4[i][r] + be1[ch];
            } else {
                int ch = 16 * (ct4 - 8) + lp;
                pbh[(size_t)node * 128 + ch] = f2bf(acc4[i][r]);
            }
        }
    }
}

// -------- K3F: FUSED edge + node-update kernel. Edge phase = R2's g-paired
// t-outer structure (unchanged math). Node phase: this block's 4 target nodes
// get their full update here (agg never leaves LDS).
// Cross-block hazards within one launch, and their fixes:
//   X   — read (cols) by edge, written by node  -> PARITY buffers OFF_X/OFF_DX
//   PBH — read (cols) by edge, written by node  -> PARITY buffers OFF_PBH/OFF_PBH2
//         (R3 bug: single-buffered PBH raced; fast blocks overwrote pb(l) with
//          pb(l+1) while slow blocks were still consuming pb(l) as columns)
//   PA/H — block-local only (own 4 nodes), ordered within the block.
#define KG 4
#define SMC_BS    0        // short[2048][8] swizzled = 32768
#define SMC_AGG   32768    // float[4][6][128] = 12288
#define SMC_PE0   45056    // float[KG*128] = 2048   | node: haggS short[4][256] = 2048
#define SMC_PE1   47104    // float[KG*128] = 2048   | node: hS short[4][136] = 1088
#define SMC_WC    49152    // float[128] = 512
#define SMC_BE2   49664    // float[128] = 512
#define SMC_WX    50176    // float[128] = 512       | node l==2: redS float[16]
#define SMC_COEF  50688    // float[4][96] = 1536    | node: uS short[4][136] = 1088
#define SMC_XT    52224    // float[12] = 48
#define SMC_CI    52272    // int[4] = 16
#define SMC_XN    52288    // float[12] = 48 (updated X of own nodes) -> total 52336
__global__ void __launch_bounds__(384)
k3f_edge_node(const float* __restrict__ We1, const float* __restrict__ Wx,
              const float* __restrict__ be2, const int* __restrict__ chain,
              const float* __restrict__ bh1, const float* __restrict__ bh2,
              const float* __restrict__ be1, const float* __restrict__ bout,
              const float* __restrict__ H0, const float* __restrict__ X0,
              const float* __restrict__ H1, const float* __restrict__ X1,
              const int* __restrict__ gmask, const int* __restrict__ shiftp,
              int l, float* __restrict__ ws, float* __restrict__ out) {
    __shared__ __align__(16) char smem[52336];
    short* bS    = (short*)(smem + SMC_BS);
    float* aggP  = (float*)(smem + SMC_AGG);
    float* pe0S  = (float*)(smem + SMC_PE0);
    float* pe1S  = (float*)(smem + SMC_PE1);
    float* wcS   = (float*)(smem + SMC_WC);
    float* be2S  = (float*)(smem + SMC_BE2);
    float* wxS   = (float*)(smem + SMC_WX);
    float* coefS = (float*)(smem + SMC_COEF);
    float* xT    = (float*)(smem + SMC_XT);
    int*   ciS   = (int*)  (smem + SMC_CI);
    float* xnS   = (float*)(smem + SMC_XN);

    int tid = threadIdx.x;
    int i0 = blockIdx.x * KG;
    int colbase = (i0 / 96) * 96;
    const float* Xin  = ws + ((l & 1) ? OFF_DX : OFF_X);
    float*       Xout = ws + ((l & 1) ? OFF_X  : OFF_DX);
    const short* pbh_in  = (const short*)(ws + ((l & 1) ? OFF_PBH2 : OFF_PBH));
    short*       pbh_out = (short*)      (ws + ((l & 1) ? OFF_PBH  : OFF_PBH2));

    // ---- stage: swizzled B + fused pe0/pe1 + wc + be2/wx
    {
        const short* bpe = (const short*)(ws + OFF_BPE) + (size_t)l * 128 * 128;
        for (int idx = tid; idx < 2048; idx += 384) {
            int t = idx >> 8, s = (idx >> 6) & 3, ln = idx & 63;
            int lq = ln >> 4, lpp = ln & 15;
            *(bf16x8*)(bS + idx * 8) =
                *(const bf16x8*)(bpe + (size_t)(16 * t + lpp) * 128 + s * 32 + lq * 8);
        }
        if (tid < 128) {
            float et0 = ws[OFF_ET + l * 256 + tid];
            float et1 = ws[OFF_ET + l * 256 + 128 + tid];
            #pragma unroll
            for (int g = 0; g < KG; g++) {
                float pav = ws[OFF_PA + (size_t)(i0 + g) * 128 + tid];
                pe0S[g * 128 + tid] = pav + et0;
                pe1S[g * 128 + tid] = pav + et1;
            }
            wcS[tid]  = We1[(l * 289 + 256) * 128 + tid];
            be2S[tid] = be2[l * 128 + tid];
            wxS[tid]  = Wx[l * 128 + tid];
        }
        if (tid < KG * 3) xT[tid] = Xin[(size_t)(i0 + tid / 3) * 3 + tid % 3];
        if (tid < KG) ciS[tid] = chain[i0 + tid];
    }

    int w = tid >> 6, lane = tid & 63;
    int quad = lane >> 4, lp = lane & 15;
    int jA = 16 * w + lp;                       // lane's fixed source row
    const short* pbrow = pbh_in + (size_t)(colbase + jA) * 128;
    float xr0 = Xin[(size_t)(colbase + jA) * 3 + 0];
    float xr1 = Xin[(size_t)(colbase + jA) * 3 + 1];
    float xr2 = Xin[(size_t)(colbase + jA) * 3 + 2];
    int cj = chain[colbase + jA];
    // epilogue x hoists (waves 0..2 only use them)
    float ex0 = 0.f, ex1 = 0.f;
    if (w < 3) {
        ex0 = Xin[(size_t)(colbase + lane) * 3 + w];
        if (lane < 32) ex1 = Xin[(size_t)(colbase + lane + 64) * 3 + w];
    }
    __syncthreads();

    #pragma unroll
    for (int gr = 0; gr < 2; gr++) {
        int g0 = 2 * gr, g1 = 2 * gr + 1;
        // ---- A-build for the pair (g0, g1)
        float rx0 = xT[g0 * 3 + 0] - xr0, ry0 = xT[g0 * 3 + 1] - xr1, rz0 = xT[g0 * 3 + 2] - xr2;
        float rx1 = xT[g1 * 3 + 0] - xr0, ry1 = xT[g1 * 3 + 1] - xr1, rz1 = xT[g1 * 3 + 2] - xr2;
        float d20 = rx0 * rx0 + ry0 * ry0 + rz0 * rz0;
        float d21 = rx1 * rx1 + ry1 * ry1 + rz1 * rz1;
        const float* peB0 = ((cj != ciS[g0]) ? pe1S : pe0S) + g0 * 128;
        const float* peB1 = ((cj != ciS[g1]) ? pe1S : pe0S) + g1 * 128;

        bf16x8 af0[4], af1[4];
        #pragma unroll
        for (int s = 0; s < 4; s++) {
            int kb = s * 32 + quad * 8;
            bf16x8 pb = *(const bf16x8*)(pbrow + kb);   // L2-hot reload
            float4 w0 = *(const float4*)(wcS + kb);
            float4 w1 = *(const float4*)(wcS + kb + 4);
            float wcv[8] = {w0.x, w0.y, w0.z, w0.w, w1.x, w1.y, w1.z, w1.w};
            float4 pa0 = *(const float4*)(peB0 + kb);
            float4 pa1 = *(const float4*)(peB0 + kb + 4);
            float4 pb0 = *(const float4*)(peB1 + kb);
            float4 pb1 = *(const float4*)(peB1 + kb + 4);
            float pe0v[8] = {pa0.x, pa0.y, pa0.z, pa0.w, pa1.x, pa1.y, pa1.z, pa1.w};
            float pe1v[8] = {pb0.x, pb0.y, pb0.z, pb0.w, pb1.x, pb1.y, pb1.z, pb1.w};
            float z0[8], z1[8];
            #pragma unroll
            for (int e = 0; e < 8; e++) {
                float pbf = bf2f(pb[e]);
                z0[e] = silu(pe0v[e] + pbf + d20 * wcv[e]);
                z1[e] = silu(pe1v[e] + pbf + d21 * wcv[e]);
            }
            #pragma unroll
            for (int e = 0; e < 8; e += 2) {
                short2 p0 = f2bf2(z0[e], z0[e + 1]);
                short2 p1 = f2bf2(z1[e], z1[e + 1]);
                af0[s][e] = p0.x; af0[s][e + 1] = p0.y;
                af1[s][e] = p1.x; af1[s][e + 1] = p1.y;
            }
        }

        // ---- t-outer MFMA loop: each B fragment read ONCE for both g
        float cp0[4] = {0.f, 0.f, 0.f, 0.f};
        float cp1[4] = {0.f, 0.f, 0.f, 0.f};
        #pragma unroll
        for (int t = 0; t < 8; t++) {
            f32x4 a0 = (f32x4){0.f, 0.f, 0.f, 0.f};
            f32x4 a1 = (f32x4){0.f, 0.f, 0.f, 0.f};
            #pragma unroll
            for (int s = 0; s < 4; s++) {
                bf16x8 bf = *(const bf16x8*)(bS + ((t * 4 + s) * 64 + lane) * 8);
                a0 = __builtin_amdgcn_mfma_f32_16x16x32_bf16(af0[s], bf, a0, 0, 0, 0);
                a1 = __builtin_amdgcn_mfma_f32_16x16x32_bf16(af1[s], bf, a1, 0, 0, 0);
            }
            float be2v = be2S[16 * t + lp];
            float wxv  = wxS[16 * t + lp];
            float ag0 = 0.f, ag1 = 0.f;
            #pragma unroll
            for (int r = 0; r < 4; r++) {
                float m20 = silu(a0[r] + be2v);
                float m21 = silu(a1[r] + be2v);
                ag0 += m20; ag1 += m21;
                cp0[r] += m20 * wxv;
                cp1[r] += m21 * wxv;
            }
            ag0 += __shfl_xor(ag0, 16); ag0 += __shfl_xor(ag0, 32);
            ag1 += __shfl_xor(ag1, 16); ag1 += __shfl_xor(ag1, 32);
            if (lane < 16) {
                aggP[(g0 * 6 + w) * 128 + 16 * t + lp] = ag0;
                aggP[(g1 * 6 + w) * 128 + 16 * t + lp] = ag1;
            }
        }
        #pragma unroll
        for (int r = 0; r < 4; r++) {
            float v0 = cp0[r], v1 = cp1[r];
            v0 += __shfl_xor(v0, 1); v1 += __shfl_xor(v1, 1);
            v0 += __shfl_xor(v0, 2); v1 += __shfl_xor(v1, 2);
            v0 += __shfl_xor(v0, 4); v1 += __shfl_xor(v1, 4);
            v0 += __shfl_xor(v0, 8); v1 += __shfl_xor(v1, 8);
            if (lp == 0) {
                coefS[g0 * 96 + 16 * w + quad * 4 + r] = v0;
                coefS[g1 * 96 + 16 * w + quad * 4 + r] = v1;
            }
        }
        __syncthreads();

        // ---- dX tail for this pair: X_next = X_cur + dX (parity write, no race)
        if (w < 3) {
            #pragma unroll
            for (int gg = 0; gg < 2; gg++) {
                int g = 2 * gr + gg;
                float v = (xT[g * 3 + w] - ex0) * coefS[g * 96 + lane];
                if (lane < 32) v += (xT[g * 3 + w] - ex1) * coefS[g * 96 + lane + 64];
                #pragma unroll
                for (int o = 32; o > 0; o >>= 1) v += __shfl_down(v, o);
                if (lane == 0) {
                    float xv = xT[g * 3 + w] + v;
                    Xout[(size_t)(i0 + g) * 3 + w] = xv;
                    xnS[g * 3 + w] = xv;
                }
            }
        }
    }

    // ================= node phase (this block's 4 nodes) =================
    short* haggS = (short*)(smem + SMC_PE0);   // [4][256] bf16: [h | agg]
    short* uS    = (short*)(smem + SMC_COEF);  // [4][136] bf16
    short* hS    = (short*)(smem + SMC_PE1);   // [4][136] bf16
    const bf16x8 zf = (bf16x8){0, 0, 0, 0, 0, 0, 0, 0};

    // build [h | agg] (agg = sum of the 6 per-wave partials, same order as before)
    for (int idx = tid; idx < 1024; idx += 384) {
        int g = idx >> 8, c = idx & 255;
        float v;
        if (c < 128) {
            v = ws[OFF_H + (size_t)(i0 + g) * 128 + c];
        } else {
            int ch = c - 128;
            v = 0.f;
            #pragma unroll
            for (int q = 0; q < 6; q++) v += aggP[(g * 6 + q) * 128 + ch];
        }
        haggS[g * 256 + c] = f2bf(v);
    }
    if (l == 2 && tid < 16) ((float*)(smem + SMC_WX))[tid] = 0.f;
    __syncthreads();

    // ---- GEMM1: [h|agg] @ Wh1, M=4(16), K=256, N=128 -> u (silu)
    {
        const short* b1 = (const short*)(ws + OFF_BH1) + (size_t)l * 128 * 256;
        for (int ct = w; ct < 8; ct += 6) {
            f32x4 acc = (f32x4){0.f, 0.f, 0.f, 0.f};
            #pragma unroll
            for (int s = 0; s < 8; s++) {
                int kb = s * 32 + quad * 8;
                bf16x8 af = zf;
                if (lp < 4) af = *(const bf16x8*)(haggS + lp * 256 + kb);
                bf16x8 bf = *(const bf16x8*)(b1 + (size_t)(16 * ct + lp) * 256 + kb);
                acc = __builtin_amdgcn_mfma_f32_16x16x32_bf16(af, bf, acc, 0, 0, 0);
            }
            if (quad == 0) {
                int ch = 16 * ct + lp;
                float bb = bh1[l * 128 + ch];
                #pragma unroll
                for (int r = 0; r < 4; r++)
                    uS[r * 136 + ch] = f2bf(silu(acc[r] + bb));
            }
        }
    }
    __syncthreads();

    // ---- GEMM2: u @ Wh2, K=128 -> h += ; hS = bf16(h)
    {
        const short* b2 = (const short*)(ws + OFF_BH2) + (size_t)l * 128 * 128;
        for (int ct = w; ct < 8; ct += 6) {
            f32x4 acc = (f32x4){0.f, 0.f, 0.f, 0.f};
            #pragma unroll
            for (int s = 0; s < 4; s++) {
                int kb = s * 32 + quad * 8;
                bf16x8 af = zf;
                if (lp < 4) af = *(const bf16x8*)(uS + lp * 136 + kb);
                bf16x8 bf = *(const bf16x8*)(b2 + (size_t)(16 * ct + lp) * 128 + kb);
                acc = __builtin_amdgcn_mfma_f32_16x16x32_bf16(af, bf, acc, 0, 0, 0);
            }
            if (quad == 0) {
                int ch = 16 * ct + lp;
                float bb = bh2[l * 128 + ch];
                #pragma unroll
                for (int r = 0; r < 4; r++) {
                    size_t off = OFF_H + (size_t)(i0 + r) * 128 + ch;
                    float h = ws[off] + acc[r] + bb;
                    ws[off] = h;
                    hS[r * 136 + ch] = f2bf(h);
                }
            }
        }
    }
    __syncthreads();

    if (l < 2) {
        // ---- GEMM3: pa/pb for layer l+1, K=128, N=256 -> parity-out buffers
        const short* bab = (const short*)(ws + OFF_BAB) + (size_t)(l + 1) * 256 * 128;
        for (int ct4 = w; ct4 < 16; ct4 += 6) {
            f32x4 acc = (f32x4){0.f, 0.f, 0.f, 0.f};
            #pragma unroll
            for (int s = 0; s < 4; s++) {
                int kb = s * 32 + quad * 8;
                bf16x8 af = zf;
                if (lp < 4) af = *(const bf16x8*)(hS + lp * 136 + kb);
                bf16x8 bf = *(const bf16x8*)(bab + (size_t)(16 * ct4 + lp) * 128 + kb);
                acc = __builtin_amdgcn_mfma_f32_16x16x32_bf16(af, bf, acc, 0, 0, 0);
            }
            if (quad == 0) {
                #pragma unroll
                for (int r = 0; r < 4; r++) {
                    int node = i0 + r;
                    if (ct4 < 8) {
                        int ch = 16 * ct4 + lp;
                        ws[OFF_PA + (size_t)node * 128 + ch] = acc[r] + be1[(l + 1) * 128 + ch];
                    } else {
                        int ch = 16 * (ct4 - 8) + lp;
                        pbh_out[(size_t)node * 128 + ch] = f2bf(acc[r]);
                    }
                }
            }
        }
    } else {
        // ---- l==2: v = h @ Wout^T (N=64, waves 0..3) + loss + 768-WG election
        float* redS = (float*)(smem + SMC_WX);
        const short* bwo = (const short*)(ws + OFF_BWO);
        f32x4 accv = (f32x4){0.f, 0.f, 0.f, 0.f};
        bool act = (w < 4);
        if (act) {
            #pragma unroll
            for (int s = 0; s < 4; s++) {
                int kb = s * 32 + quad * 8;
                bf16x8 af = zf;
                if (lp < 4) af = *(const bf16x8*)(hS + lp * 136 + kb);
                bf16x8 bf = *(const bf16x8*)(bwo + (size_t)(16 * w + lp) * 128 + kb);
                accv = __builtin_amdgcn_mfma_f32_16x16x32_bf16(af, bf, accv, 0, 0, 0);
            }
        }
        int sft = shiftp[0] % NN; if (sft < 0) sft += NN;
        float ep = 0.f, en = 0.f;
        if (act && quad == 0) {
            int col = 16 * w + lp;
            float bo = bout[col];
            #pragma unroll
            for (int r = 0; r < 4; r++) {
                int node = i0 + r;
                if (gmask[node] != 0) {
                    int ip = node + sft; if (ip >= NN) ip -= NN;
                    float v  = accv[r] + bo;
                    float tp = H1[(size_t)node * 64 + col] - H0[(size_t)node * 64 + col];
                    float tn = H1[(size_t)ip * 64 + col]  - H0[(size_t)ip * 64 + col];
                    float dp = v - tp, dn = v - tn;
                    ep += dp * dp;
                    en += dn * dn;
                }
            }
        }
        ep += __shfl_xor(ep, 1); en += __shfl_xor(en, 1);
        ep += __shfl_xor(ep, 2); en += __shfl_xor(en, 2);
        ep += __shfl_xor(ep, 4); en += __shfl_xor(en, 4);
        ep += __shfl_xor(ep, 8); en += __shfl_xor(en, 8);
        if (act && lane == 0) { redS[w] = ep; redS[4 + w] = en; }

        if (tid < 12) {
            int g = tid / 3, d = tid % 3;
            int node = i0 + g;
            if (gmask[node] != 0) {
                int ip = node + sft; if (ip >= NN) ip -= NN;
                float xv  = xnS[g * 3 + d];
                float tpx = X1[(size_t)node * 3 + d] - X0[(size_t)node * 3 + d];
                float tnx = X1[(size_t)ip * 3 + d]   - X0[(size_t)ip * 3 + d];
                atomicAdd(&redS[8], (xv - tpx) * (xv - tpx));
                atomicAdd(&redS[9], (xv - tnx) * (xv - tnx));
            }
        }
        if (tid < 4) {
            if (gmask[i0 + tid] != 0) atomicAdd(&redS[10], 1.0f);
        }
        __syncthreads();
        if (tid == 0) {
            float eT = redS[0] + redS[1] + redS[2] + redS[3];
            float nT = redS[4] + redS[5] + redS[6] + redS[7];
            float* acc0 = ws + OFF_ACC;
            atomicAdd(acc0 + 0, eT);
            atomicAdd(acc0 + 2, nT);
            atomicAdd(acc0 + 1, redS[8]);
            atomicAdd(acc0 + 3, redS[9]);
            atomicAdd(acc0 + 4, redS[10]);
            // ---- final election among the 768 l==2 WGs: write out
            __threadfence();
            unsigned o2 = atomicAdd((unsigned*)(ws + OFF_CNT) + 96, 1u);
            if (o2 == 767u) {
                __threadfence();
                float a0 = atomicAdd(acc0 + 0, 0.0f);
                float a1 = atomicAdd(acc0 + 1, 0.0f);
                float a2 = atomicAdd(acc0 + 2, 0.0f);
                float a3 = atomicAdd(acc0 + 3, 0.0f);
                float a4 = atomicAdd(acc0 + 4, 0.0f);
                float msum = a4 + 1e-8f;
                float lhp = a0 / msum, lxp = a1 / msum;
                float lhn = a2 / msum, lxn = a3 / msum;
                out[0] = lhp - 0.05f * lhn;
                out[1] = lxp - 0.05f * lxn;
                out[2] = lhp;
                out[3] = lxp;
                out[4] = lhn;
                out[5] = lxn;
            }
        }
    }
}

extern "C" void kernel_launch(void* const* d_in, const int* in_sizes, int n_in,
                              void* d_out, int out_size, void* d_ws, size_t ws_size,
                              hipStream_t stream) {
    (void)in_sizes; (void)n_in; (void)out_size; (void)ws_size;
    const float* H0   = (const float*)d_in[0];
    const float* X0   = (const float*)d_in[1];
    const float* H1   = (const float*)d_in[2];
    const float* X1   = (const float*)d_in[3];
    const float* cond = (const float*)d_in[4];
    const float* tg   = (const float*)d_in[5];
    const float* Wi1  = (const float*)d_in[6];
    const float* bi1  = (const float*)d_in[7];
    const float* Wi2  = (const float*)d_in[8];
    const float* bi2  = (const float*)d_in[9];
    const float* Wi3  = (const float*)d_in[10];
    const float* bi3  = (const float*)d_in[11];
    const float* etab = (const float*)d_in[12];
    const float* We1  = (const float*)d_in[13];
    const float* be1  = (const float*)d_in[14];
    const float* We2  = (const float*)d_in[15];
    const float* be2  = (const float*)d_in[16];
    const float* Wx   = (const float*)d_in[17];
    const float* Wh1  = (const float*)d_in[18];
    const float* bh1  = (const float*)d_in[19];
    const float* Wh2  = (const float*)d_in[20];
    const float* bh2  = (const float*)d_in[21];
    const float* Wout = (const float*)d_in[22];
    const float* bout = (const float*)d_in[23];
    const int* chain   = (const int*)d_in[25];
    const int* gmask   = (const int*)d_in[26];
    const int* lengths = (const int*)d_in[27];
    const int* shiftp  = (const int*)d_in[28];
    float* ws  = (float*)d_ws;
    float* out = (float*)d_out;

    k0_all<<<1473, 256, 0, stream>>>(etab, We1, lengths, We2, Wh1, Wh2,
                                     Wout, Wi1, Wi2, Wi3, ws);
    k1s_node_init<<<dim3(NBATCH, 6), 256, 0, stream>>>(H0, X0, H1, X1, cond, tg,
                                                       bi1, bi2, bi3, be1, gmask, ws);
    for (int l = 0; l < 3; l++) {
        k3f_edge_node<<<NN / KG, 384, 0, stream>>>(We1, Wx, be2, chain,
                                                   bh1, bh2, be1, bout,
                                                   H0, X0, H1, X1, gmask, shiftp,
                                                   l, ws, out);
    }
}

// Round 5
// 378.224 us; speedup vs baseline: 1.0921x; 1.0921x over previous
//
#include <hip/hip_runtime.h>
#include <hip/hip_bf16.h>
#include <math.h>

// Problem constants
#define NBATCH 32
#define LSEQ   96
#define NN     3072
#define HID    128
#define LAT    64
#define EEMB   32

// Workspace layout (float offsets). Total ~6.35 MB.
#define OFF_H      0                          // N x 128 fp32
#define OFF_X      (OFF_H   + NN*HID)         // N x 3
#define OFF_PA     (OFF_X   + NN*3)           // N x 128 fp32 (pa + be1)
#define OFF_AGG    (OFF_PA  + NN*HID)         // N x 128
#define OFF_DX     (OFF_AGG + NN*HID)         // N x 3
#define OFF_ET     (OFF_DX  + NN*3)           // 3*2*128 fp32
#define OFF_ACC    (OFF_ET  + 768)            // 8
#define OFF_NBID   (OFF_ACC + 8)              // N int
#define OFF_CUM    (OFF_NBID + NN)            // 40 int
#define OFF_PBH    (OFF_CUM + 40)             // N x 128 bf16 (as 196608 floats)
#define OFF_BPE    (OFF_PBH + NN*HID/2)       // We2^T  bf16: 3*128*128 -> 24576 floats
#define OFF_BAB    (OFF_BPE + 24576)          // We1[0:256]^T bf16: 3*256*128 -> 49152
#define OFF_BH1    (OFF_BAB + 49152)          // Wh1^T bf16: 3*128*256 -> 49152
#define OFF_BH2    (OFF_BH1 + 49152)          // Wh2^T bf16: 3*128*128 -> 24576
#define OFF_BWO    (OFF_BH2 + 24576)          // Wout^T bf16: 64*128 -> 4096 floats
#define OFF_BWI1   (OFF_BWO + 4096)           // Wi1^T bf16: 128x320 -> 20480 floats
#define OFF_BWI2   (OFF_BWI1 + 20480)         // Wi2^T bf16: 128x128 -> 8192 floats
#define OFF_BWI3   (OFF_BWI2 + 8192)          // Wi3^T bf16: 128x128 -> 8192 floats
#define OFF_CNT    (OFF_BWI3 + 8192)          // 128 uint: [96] = final-election counter

typedef short bf16x8 __attribute__((ext_vector_type(8)));
typedef float f32x4  __attribute__((ext_vector_type(4)));

__device__ __forceinline__ short f2bf(float f) {
    unsigned u = __builtin_bit_cast(unsigned, f);
    unsigned r = (u + 0x7FFFu + ((u >> 16) & 1u)) >> 16;
    return (short)r;
}
__device__ __forceinline__ short2 f2bf2(float a, float b) {
    __hip_bfloat162 h = __float22bfloat162_rn(make_float2(a, b));
    short2 r;
    __builtin_memcpy(&r, &h, sizeof(r));
    return r;
}
__device__ __forceinline__ float bf2f(short s) {
    unsigned u = ((unsigned)(unsigned short)s) << 16;
    return __builtin_bit_cast(float, u);
}
__device__ __forceinline__ float silu(float z) {
    return z * __builtin_amdgcn_rcpf(1.0f + __expf(-z));
}

// --------------------- K0: prep + weight transposes (merged)
__global__ void k0_all(const float* __restrict__ edge_table, const float* __restrict__ We1,
                       const int* __restrict__ lengths, const float* __restrict__ We2,
                       const float* __restrict__ Wh1, const float* __restrict__ Wh2,
                       const float* __restrict__ Wout, const float* __restrict__ Wi1,
                       const float* __restrict__ Wi2, const float* __restrict__ Wi3,
                       float* __restrict__ ws) {
    int tid = threadIdx.x;
    if (blockIdx.x == 1472) {
        int* cum = (int*)(ws + OFF_CUM);
        int* nb  = (int*)(ws + OFF_NBID);
        float* et = ws + OFF_ET;
        if (tid == 0) {
            int s = 0;
            for (int b = 0; b < NBATCH; b++) { cum[b] = s; s += lengths[b]; }
            cum[NBATCH] = s;
        }
        if (tid < 8) ws[OFF_ACC + tid] = 0.0f;
        if (tid < 128) ((unsigned*)(ws + OFF_CNT))[tid] = 0u;
        __syncthreads();
        for (int i = tid; i < NN; i += blockDim.x) {
            int b = NBATCH - 1;
            for (int q = 0; q < NBATCH; q++) { if (i < cum[q + 1]) { b = q; break; } }
            nb[i] = b;
        }
        for (int idx = tid; idx < 3 * 2 * HID; idx += blockDim.x) {
            int c = idx & 127;
            int t = (idx >> 7) & 1;
            int l = idx >> 8;
            const float* w = We1 + (l * 289 + 257) * HID + c;
            const float* e = edge_table + t * EEMB;
            float s = 0.f;
            for (int k = 0; k < EEMB; k++) s += e[k] * w[k * HID];
            et[idx] = s;
        }
        return;
    }
    int idx = blockIdx.x * 256 + tid;   // 0 .. 376831
    short* bpe  = (short*)(ws + OFF_BPE);
    short* bab  = (short*)(ws + OFF_BAB);
    short* bh1  = (short*)(ws + OFF_BH1);
    short* bh2  = (short*)(ws + OFF_BH2);
    short* bwo  = (short*)(ws + OFF_BWO);
    short* bwi1 = (short*)(ws + OFF_BWI1);
    short* bwi2 = (short*)(ws + OFF_BWI2);
    short* bwi3 = (short*)(ws + OFF_BWI3);
    if (idx < 49152) {
        int k = idx & 127, n = (idx >> 7) & 127, l = idx >> 14;
        bpe[idx] = f2bf(We2[(l * 128 + k) * 128 + n]);
    } else if (idx < 147456) {
        int q = idx - 49152;
        int k = q & 127, n = (q >> 7) & 255, l = q >> 15;
        float v = (n < 128) ? We1[(l * 289 + k) * 128 + n]
                            : We1[(l * 289 + 128 + k) * 128 + (n - 128)];
        bab[q] = f2bf(v);
    } else if (idx < 245760) {
        int q = idx - 147456;
        int k = q & 255, n = (q >> 8) & 127, l = q >> 15;
        bh1[q] = f2bf(Wh1[(l * 256 + k) * 128 + n]);
    } else if (idx < 294912) {
        int q = idx - 245760;
        int k = q & 127, n = (q >> 7) & 127, l = q >> 14;
        bh2[q] = f2bf(Wh2[(l * 128 + k) * 128 + n]);
    } else if (idx < 303104) {
        int q = idx - 294912;
        int k = q & 127, n = q >> 7;          // n < 64
        bwo[q] = f2bf(Wout[k * 64 + n]);
    } else if (idx < 344064) {
        int q = idx - 303104;                  // [n<128][k<320]
        int n = q / 320, k = q - n * 320;
        bwi1[q] = f2bf(Wi1[k * 128 + n]);
    } else if (idx < 360448) {
        int q = idx - 344064;
        int k = q & 127, n = q >> 7;
        bwi2[q] = f2bf(Wi2[k * 128 + n]);
    } else if (idx < 376832) {
        int q = idx - 360448;
        int k = q & 127, n = q >> 7;
        bwi3[q] = f2bf(Wi3[k * 128 + n]);
    }
}

// ------------- K1s: init MLP row-split — grid (32, 6), 256 thr, 16 nodes/WG
__global__ void __launch_bounds__(256)
k1s_node_init(const float* __restrict__ H0, const float* __restrict__ X0,
              const float* __restrict__ H1, const float* __restrict__ X1,
              const float* __restrict__ cond, const float* __restrict__ tg,
              const float* __restrict__ bi1, const float* __restrict__ bi2,
              const float* __restrict__ bi3, const float* __restrict__ be1,
              const int* __restrict__ gmask, float* __restrict__ ws) {
    __shared__ short u1[16 * 136];
    __shared__ short u2[16 * 136];
    int rowbase = blockIdx.x * 96 + blockIdx.y * 16;
    int tid = threadIdx.x;
    int w = tid >> 6, lane = tid & 63;
    int quad = lane >> 4, lp = lane & 15;
    int nodeA = rowbase + lp;
    const int* nb = (const int*)(ws + OFF_NBID);
    float t = tg[nb[nodeA]];
    float u = (gmask[nodeA] != 0) ? t : 1.0f;

    if (tid < 48) {
        int node = rowbase + tid / 3, d = tid % 3;
        float tn = tg[nb[node]];
        float un = (gmask[node] != 0) ? tn : 1.0f;
        ws[OFF_X + (size_t)node * 3 + d] =
            (1.0f - un) * X0[(size_t)node * 3 + d] + un * X1[(size_t)node * 3 + d];
    }

    const short* bwi1 = (const short*)(ws + OFF_BWI1);
    const short* bwi2 = (const short*)(ws + OFF_BWI2);
    const short* bwi3 = (const short*)(ws + OFF_BWI3);
    const short* bab  = (const short*)(ws + OFF_BAB);   // l = 0

    // ---- GEMM1: K=320
    f32x4 acc[2];
    acc[0] = (f32x4){0.f, 0.f, 0.f, 0.f};
    acc[1] = (f32x4){0.f, 0.f, 0.f, 0.f};
    for (int s = 0; s < 10; s++) {
        int kb = s * 32 + quad * 8;
        float z[8];
        if (kb < 64) {
            const float* h0 = H0 + (size_t)nodeA * 64 + kb;
            const float* h1 = H1 + (size_t)nodeA * 64 + kb;
            #pragma unroll
            for (int e = 0; e < 8; e++) z[e] = (1.0f - u) * h0[e] + u * h1[e];
        } else if (kb < 192) {
            const float* cp = cond + (size_t)nodeA * 128 + (kb - 64);
            #pragma unroll
            for (int e = 0; e < 8; e++) z[e] = cp[e];
        } else if (kb < 256) {
            #pragma unroll
            for (int e = 0; e < 8; e++) {
                float c = (float)(kb - 192 + e);
                float fr = __expf(-9.2103403719761836f * c / 63.0f);
                z[e] = __sinf(t * fr);
            }
        } else {
            #pragma unroll
            for (int e = 0; e < 8; e++) {
                float c = (float)(kb - 256 + e);
                float fr = __expf(-9.2103403719761836f * c / 63.0f);
                z[e] = __cosf(t * fr);
            }
        }
        bf16x8 af;
        #pragma unroll
        for (int e = 0; e < 8; e += 2) {
            short2 p = f2bf2(z[e], z[e + 1]);
            af[e] = p.x; af[e + 1] = p.y;
        }
        #pragma unroll
        for (int i = 0; i < 2; i++) {
            int ct = 2 * w + i;
            bf16x8 bf = *(const bf16x8*)(bwi1 + (size_t)(16 * ct + lp) * 320 + kb);
            acc[i] = __builtin_amdgcn_mfma_f32_16x16x32_bf16(af, bf, acc[i], 0, 0, 0);
        }
    }
    #pragma unroll
    for (int i = 0; i < 2; i++) {
        int ch = 16 * (2 * w + i) + lp;
        float bb1 = bi1[ch];
        #pragma unroll
        for (int r = 0; r < 4; r++)
            u1[(quad * 4 + r) * 136 + ch] = f2bf(fmaxf(acc[i][r] + bb1, 0.0f));
    }
    __syncthreads();

    // ---- GEMM2: K=128
    acc[0] = (f32x4){0.f, 0.f, 0.f, 0.f};
    acc[1] = (f32x4){0.f, 0.f, 0.f, 0.f};
    #pragma unroll
    for (int s = 0; s < 4; s++) {
        int kb = s * 32 + quad * 8;
        bf16x8 af = *(const bf16x8*)(u1 + lp * 136 + kb);
        #pragma unroll
        for (int i = 0; i < 2; i++) {
            int ct = 2 * w + i;
            bf16x8 bf = *(const bf16x8*)(bwi2 + (size_t)(16 * ct + lp) * 128 + kb);
            acc[i] = __builtin_amdgcn_mfma_f32_16x16x32_bf16(af, bf, acc[i], 0, 0, 0);
        }
    }
    #pragma unroll
    for (int i = 0; i < 2; i++) {
        int ch = 16 * (2 * w + i) + lp;
        float bb2 = bi2[ch];
        #pragma unroll
        for (int r = 0; r < 4; r++)
            u2[(quad * 4 + r) * 136 + ch] = f2bf(fmaxf(acc[i][r] + bb2, 0.0f));
    }
    __syncthreads();

    // ---- GEMM3: K=128 -> h (no relu)
    acc[0] = (f32x4){0.f, 0.f, 0.f, 0.f};
    acc[1] = (f32x4){0.f, 0.f, 0.f, 0.f};
    #pragma unroll
    for (int s = 0; s < 4; s++) {
        int kb = s * 32 + quad * 8;
        bf16x8 af = *(const bf16x8*)(u2 + lp * 136 + kb);
        #pragma unroll
        for (int i = 0; i < 2; i++) {
            int ct = 2 * w + i;
            bf16x8 bf = *(const bf16x8*)(bwi3 + (size_t)(16 * ct + lp) * 128 + kb);
            acc[i] = __builtin_amdgcn_mfma_f32_16x16x32_bf16(af, bf, acc[i], 0, 0, 0);
        }
    }
    #pragma unroll
    for (int i = 0; i < 2; i++) {
        int ch = 16 * (2 * w + i) + lp;
        float bb3 = bi3[ch];
        #pragma unroll
        for (int r = 0; r < 4; r++) {
            int row = quad * 4 + r;
            float h = acc[i][r] + bb3;
            ws[OFF_H + (size_t)(rowbase + row) * 128 + ch] = h;
            u1[row * 136 + ch] = f2bf(h);
        }
    }
    __syncthreads();

    // ---- GEMM4: pa/pb layer 0, N=256 (ct4 = 4w..4w+3)
    f32x4 acc4[4];
    #pragma unroll
    for (int i = 0; i < 4; i++) acc4[i] = (f32x4){0.f, 0.f, 0.f, 0.f};
    #pragma unroll
    for (int s = 0; s < 4; s++) {
        int kb = s * 32 + quad * 8;
        bf16x8 af = *(const bf16x8*)(u1 + lp * 136 + kb);
        #pragma unroll
        for (int i = 0; i < 4; i++) {
            int ct4 = 4 * w + i;
            bf16x8 bf = *(const bf16x8*)(bab + (size_t)(16 * ct4 + lp) * 128 + kb);
            acc4[i] = __builtin_amdgcn_mfma_f32_16x16x32_bf16(af, bf, acc4[i], 0, 0, 0);
        }
    }
    short* pbh = (short*)(ws + OFF_PBH);
    #pragma unroll
    for (int i = 0; i < 4; i++) {
        int ct4 = 4 * w + i;
        #pragma unroll
        for (int r = 0; r < 4; r++) {
            int node = rowbase + quad * 4 + r;
            if (ct4 < 8) {
                int ch = 16 * ct4 + lp;
                ws[OFF_PA + (size_t)node * 128 + ch] = acc4[i][r] + be1[ch];
            } else {
                int ch = 16 * (ct4 - 8) + lp;
                pbh[(size_t)node * 128 + ch] = f2bf(acc4[i][r]);
            }
        }
    }
}

// -------- K3w: edge kernel — R2's g-paired t-outer loop (unchanged, 55.5 µs)
#define KG 4
#define SMC_BS    0        // short[2048][8] swizzled = 32768
#define SMC_AGG   32768    // float[4][6][128] = 12288
#define SMC_PE0   45056    // float[KG*128] = 2048
#define SMC_PE1   47104    // float[KG*128] = 2048
#define SMC_WC    49152    // float[128] = 512
#define SMC_BE2   49664    // float[128] = 512
#define SMC_WX    50176    // float[128] = 512
#define SMC_COEF  50688    // float[4][96] = 1536
#define SMC_XT    52224    // float[12] = 48
#define SMC_CI    52272    // int[4] = 16  -> total 52288
__global__ void __launch_bounds__(384)
k3v_edge(const float* __restrict__ We1, const float* __restrict__ Wx,
         const float* __restrict__ be2, const int* __restrict__ chain,
         int l, float* __restrict__ ws) {
    __shared__ __align__(16) char smem[52288];
    short* bS    = (short*)(smem + SMC_BS);
    float* aggP  = (float*)(smem + SMC_AGG);
    float* pe0S  = (float*)(smem + SMC_PE0);
    float* pe1S  = (float*)(smem + SMC_PE1);
    float* wcS   = (float*)(smem + SMC_WC);
    float* be2S  = (float*)(smem + SMC_BE2);
    float* wxS   = (float*)(smem + SMC_WX);
    float* coefS = (float*)(smem + SMC_COEF);
    float* xT    = (float*)(smem + SMC_XT);
    int*   ciS   = (int*)  (smem + SMC_CI);

    int tid = threadIdx.x;
    int i0 = blockIdx.x * KG;
    int colbase = (i0 / 96) * 96;
    const float* Xc = ws + OFF_X;

    // ---- stage: swizzled B + fused pe0/pe1 + wc + be2/wx
    {
        const short* bpe = (const short*)(ws + OFF_BPE) + (size_t)l * 128 * 128;
        for (int idx = tid; idx < 2048; idx += 384) {
            int t = idx >> 8, s = (idx >> 6) & 3, ln = idx & 63;
            int lq = ln >> 4, lpp = ln & 15;
            *(bf16x8*)(bS + idx * 8) =
                *(const bf16x8*)(bpe + (size_t)(16 * t + lpp) * 128 + s * 32 + lq * 8);
        }
        if (tid < 128) {
            float et0 = ws[OFF_ET + l * 256 + tid];
            float et1 = ws[OFF_ET + l * 256 + 128 + tid];
            #pragma unroll
            for (int g = 0; g < KG; g++) {
                float pav = ws[OFF_PA + (size_t)(i0 + g) * 128 + tid];
                pe0S[g * 128 + tid] = pav + et0;
                pe1S[g * 128 + tid] = pav + et1;
            }
            wcS[tid]  = We1[(l * 289 + 256) * 128 + tid];
            be2S[tid] = be2[l * 128 + tid];
            wxS[tid]  = Wx[l * 128 + tid];
        }
        if (tid < KG * 3) xT[tid] = Xc[(size_t)(i0 + tid / 3) * 3 + tid % 3];
        if (tid < KG) ciS[tid] = chain[i0 + tid];
    }

    int w = tid >> 6, lane = tid & 63;
    int quad = lane >> 4, lp = lane & 15;
    int jA = 16 * w + lp;                       // lane's fixed source row
    const short* pbrow = (const short*)(ws + OFF_PBH) + (size_t)(colbase + jA) * 128;
    float xr0 = Xc[(size_t)(colbase + jA) * 3 + 0];
    float xr1 = Xc[(size_t)(colbase + jA) * 3 + 1];
    float xr2 = Xc[(size_t)(colbase + jA) * 3 + 2];
    int cj = chain[colbase + jA];
    // epilogue x hoists (waves 0..2 only use them)
    float ex0 = 0.f, ex1 = 0.f;
    if (w < 3) {
        ex0 = Xc[(size_t)(colbase + lane) * 3 + w];
        if (lane < 32) ex1 = Xc[(size_t)(colbase + lane + 64) * 3 + w];
    }
    __syncthreads();

    #pragma unroll
    for (int gr = 0; gr < 2; gr++) {
        int g0 = 2 * gr, g1 = 2 * gr + 1;
        // ---- A-build for the pair (g0, g1)
        float rx0 = xT[g0 * 3 + 0] - xr0, ry0 = xT[g0 * 3 + 1] - xr1, rz0 = xT[g0 * 3 + 2] - xr2;
        float rx1 = xT[g1 * 3 + 0] - xr0, ry1 = xT[g1 * 3 + 1] - xr1, rz1 = xT[g1 * 3 + 2] - xr2;
        float d20 = rx0 * rx0 + ry0 * ry0 + rz0 * rz0;
        float d21 = rx1 * rx1 + ry1 * ry1 + rz1 * rz1;
        const float* peB0 = ((cj != ciS[g0]) ? pe1S : pe0S) + g0 * 128;
        const float* peB1 = ((cj != ciS[g1]) ? pe1S : pe0S) + g1 * 128;

        bf16x8 af0[4], af1[4];
        #pragma unroll
        for (int s = 0; s < 4; s++) {
            int kb = s * 32 + quad * 8;
            bf16x8 pb = *(const bf16x8*)(pbrow + kb);   // L2-hot reload
            float4 w0 = *(const float4*)(wcS + kb);
            float4 w1 = *(const float4*)(wcS + kb + 4);
            float wcv[8] = {w0.x, w0.y, w0.z, w0.w, w1.x, w1.y, w1.z, w1.w};
            float4 pa0 = *(const float4*)(peB0 + kb);
            float4 pa1 = *(const float4*)(peB0 + kb + 4);
            float4 pb0 = *(const float4*)(peB1 + kb);
            float4 pb1 = *(const float4*)(peB1 + kb + 4);
            float pe0v[8] = {pa0.x, pa0.y, pa0.z, pa0.w, pa1.x, pa1.y, pa1.z, pa1.w};
            float pe1v[8] = {pb0.x, pb0.y, pb0.z, pb0.w, pb1.x, pb1.y, pb1.z, pb1.w};
            float z0[8], z1[8];
            #pragma unroll
            for (int e = 0; e < 8; e++) {
                float pbf = bf2f(pb[e]);
                z0[e] = silu(pe0v[e] + pbf + d20 * wcv[e]);
                z1[e] = silu(pe1v[e] + pbf + d21 * wcv[e]);
            }
            #pragma unroll
            for (int e = 0; e < 8; e += 2) {
                short2 p0 = f2bf2(z0[e], z0[e + 1]);
                short2 p1 = f2bf2(z1[e], z1[e + 1]);
                af0[s][e] = p0.x; af0[s][e + 1] = p0.y;
                af1[s][e] = p1.x; af1[s][e + 1] = p1.y;
            }
        }

        // ---- t-outer MFMA loop: each B fragment read ONCE for both g
        float cp0[4] = {0.f, 0.f, 0.f, 0.f};
        float cp1[4] = {0.f, 0.f, 0.f, 0.f};
        #pragma unroll
        for (int t = 0; t < 8; t++) {
            f32x4 a0 = (f32x4){0.f, 0.f, 0.f, 0.f};
            f32x4 a1 = (f32x4){0.f, 0.f, 0.f, 0.f};
            #pragma unroll
            for (int s = 0; s < 4; s++) {
                bf16x8 bf = *(const bf16x8*)(bS + ((t * 4 + s) * 64 + lane) * 8);
                a0 = __builtin_amdgcn_mfma_f32_16x16x32_bf16(af0[s], bf, a0, 0, 0, 0);
                a1 = __builtin_amdgcn_mfma_f32_16x16x32_bf16(af1[s], bf, a1, 0, 0, 0);
            }
            float be2v = be2S[16 * t + lp];
            float wxv  = wxS[16 * t + lp];
            float ag0 = 0.f, ag1 = 0.f;
            #pragma unroll
            for (int r = 0; r < 4; r++) {
                float m20 = silu(a0[r] + be2v);
                float m21 = silu(a1[r] + be2v);
                ag0 += m20; ag1 += m21;
                cp0[r] += m20 * wxv;
                cp1[r] += m21 * wxv;
            }
            ag0 += __shfl_xor(ag0, 16); ag0 += __shfl_xor(ag0, 32);
            ag1 += __shfl_xor(ag1, 16); ag1 += __shfl_xor(ag1, 32);
            if (lane < 16) {
                aggP[(g0 * 6 + w) * 128 + 16 * t + lp] = ag0;
                aggP[(g1 * 6 + w) * 128 + 16 * t + lp] = ag1;
            }
        }
        #pragma unroll
        for (int r = 0; r < 4; r++) {
            float v0 = cp0[r], v1 = cp1[r];
            v0 += __shfl_xor(v0, 1); v1 += __shfl_xor(v1, 1);
            v0 += __shfl_xor(v0, 2); v1 += __shfl_xor(v1, 2);
            v0 += __shfl_xor(v0, 4); v1 += __shfl_xor(v1, 4);
            v0 += __shfl_xor(v0, 8); v1 += __shfl_xor(v1, 8);
            if (lp == 0) {
                coefS[g0 * 96 + 16 * w + quad * 4 + r] = v0;
                coefS[g1 * 96 + 16 * w + quad * 4 + r] = v1;
            }
        }
        __syncthreads();

        // ---- tail for this pair
        if (tid < 256) {
            int gg = tid >> 7, ch = tid & 127;
            int g = 2 * gr + gg;
            float s = 0.f;
            #pragma unroll
            for (int q = 0; q < 6; q++) s += aggP[(g * 6 + q) * 128 + ch];
            ws[OFF_AGG + (size_t)(i0 + g) * 128 + ch] = s;
        }
        if (w < 3) {
            #pragma unroll
            for (int gg = 0; gg < 2; gg++) {
                int g = 2 * gr + gg;
                float v = (xT[g * 3 + w] - ex0) * coefS[g * 96 + lane];
                if (lane < 32) v += (xT[g * 3 + w] - ex1) * coefS[g * 96 + lane + 64];
                #pragma unroll
                for (int o = 32; o > 0; o >>= 1) v += __shfl_down(v, o);
                if (lane == 0) ws[OFF_DX + (size_t)(i0 + g) * 3 + w] = v;
            }
        }
        __syncthreads();
    }
}

// ----- K4s8: node update — grid (32, 12), 512 thr (8 waves), 8 nodes/WG.
// R5 restructure: was (32,6)x256thr/16 nodes = 3 waves/CU with 64 CUs idle,
// ~5 serial latency-gated phases -> ~45 µs. Now 384 blocks x 8 waves =
// 12 waves/CU, every GEMM phase is ONE column-tile per wave (critical path
// halved), [h|agg] staged via one coalesced float4/thread into LDS
// (stride 264 shorts -> lp-strided A reads conflict-free).
__global__ void __launch_bounds__(512)
k4s_node_post(const float* __restrict__ bh1, const float* __restrict__ bh2,
              const float* __restrict__ be1, const float* __restrict__ bout,
              const float* __restrict__ H0, const float* __restrict__ X0,
              const float* __restrict__ H1, const float* __restrict__ X1,
              const int* __restrict__ gmask, const int* __restrict__ shiftp,
              int l, float* __restrict__ ws, float* __restrict__ out) {
    __shared__ short haggS[8 * 264];     // [8][264] bf16, cols 0..255 used
    __shared__ short uS[8 * 136];
    __shared__ short hS[8 * 136];
    __shared__ float redE[4], redN[4];
    __shared__ float sxp, sxn, scnt;
    int rowbase = blockIdx.x * 96 + blockIdx.y * 8;
    int tid = threadIdx.x;
    int w = tid >> 6, lane = tid & 63;
    int quad = lane >> 4, lp = lane & 15;
    const short* b1 = (const short*)(ws + OFF_BH1) + (size_t)l * 128 * 256;
    const short* b2 = (const short*)(ws + OFF_BH2) + (size_t)l * 128 * 128;
    const bf16x8 zf = (bf16x8){0, 0, 0, 0, 0, 0, 0, 0};

    if (tid == 0) { sxp = 0.f; sxn = 0.f; scnt = 0.f; }
    if (tid < 24) {
        int node = rowbase + tid / 3, d = tid % 3;
        ws[OFF_X + (size_t)node * 3 + d] += ws[OFF_DX + (size_t)node * 3 + d];
    }
    // ---- stage [h|agg] -> bf16 LDS: exactly one float4 per thread
    {
        int g = tid >> 6;                  // wave w stages node w
        int c = (tid & 63) * 4;            // 0,4,..,252
        const float* src = (c < 128)
            ? (ws + OFF_H   + (size_t)(rowbase + g) * 128 + c)
            : (ws + OFF_AGG + (size_t)(rowbase + g) * 128 + (c - 128));
        float4 v = *(const float4*)src;
        haggS[g * 264 + c + 0] = f2bf(v.x);
        haggS[g * 264 + c + 1] = f2bf(v.y);
        haggS[g * 264 + c + 2] = f2bf(v.z);
        haggS[g * 264 + c + 3] = f2bf(v.w);
    }
    __syncthreads();

    // ---- GEMM1: [h|agg] @ Wh1, M=8(16), K=256, N=128; ct = w (1 tile/wave)
    {
        f32x4 acc = (f32x4){0.f, 0.f, 0.f, 0.f};
        #pragma unroll
        for (int s = 0; s < 8; s++) {
            int kb = s * 32 + quad * 8;
            bf16x8 af = zf;
            if (lp < 8) af = *(const bf16x8*)(haggS + lp * 264 + kb);
            bf16x8 bf = *(const bf16x8*)(b1 + (size_t)(16 * w + lp) * 256 + kb);
            acc = __builtin_amdgcn_mfma_f32_16x16x32_bf16(af, bf, acc, 0, 0, 0);
        }
        if (quad < 2) {
            int ch = 16 * w + lp;
            float bb = bh1[l * 128 + ch];
            #pragma unroll
            for (int r = 0; r < 4; r++)
                uS[(quad * 4 + r) * 136 + ch] = f2bf(silu(acc[r] + bb));
        }
    }
    __syncthreads();

    // ---- GEMM2: u @ Wh2, K=128 -> h += ; hS = bf16(h); ct = w
    {
        f32x4 acc = (f32x4){0.f, 0.f, 0.f, 0.f};
        #pragma unroll
        for (int s = 0; s < 4; s++) {
            int kb = s * 32 + quad * 8;
            bf16x8 af = zf;
            if (lp < 8) af = *(const bf16x8*)(uS + lp * 136 + kb);
            bf16x8 bf = *(const bf16x8*)(b2 + (size_t)(16 * w + lp) * 128 + kb);
            acc = __builtin_amdgcn_mfma_f32_16x16x32_bf16(af, bf, acc, 0, 0, 0);
        }
        if (quad < 2) {
            int ch = 16 * w + lp;
            float bb = bh2[l * 128 + ch];
            #pragma unroll
            for (int r = 0; r < 4; r++) {
                int row = quad * 4 + r;
                size_t off = OFF_H + (size_t)(rowbase + row) * 128 + ch;
                float h = ws[off] + acc[r] + bb;
                ws[off] = h;
                hS[row * 136 + ch] = f2bf(h);
            }
        }
    }
    __syncthreads();

    if (l < 2) {
        // ---- GEMM3: pa/pb for layer l+1, K=128, N=256; ct4 = w, w+8
        const short* bab = (const short*)(ws + OFF_BAB) + (size_t)(l + 1) * 256 * 128;
        short* pbh = (short*)(ws + OFF_PBH);
        #pragma unroll
        for (int i = 0; i < 2; i++) {
            int ct4 = w + 8 * i;
            f32x4 acc = (f32x4){0.f, 0.f, 0.f, 0.f};
            #pragma unroll
            for (int s = 0; s < 4; s++) {
                int kb = s * 32 + quad * 8;
                bf16x8 af = zf;
                if (lp < 8) af = *(const bf16x8*)(hS + lp * 136 + kb);
                bf16x8 bf = *(const bf16x8*)(bab + (size_t)(16 * ct4 + lp) * 128 + kb);
                acc = __builtin_amdgcn_mfma_f32_16x16x32_bf16(af, bf, acc, 0, 0, 0);
            }
            if (quad < 2) {
                #pragma unroll
                for (int r = 0; r < 4; r++) {
                    int node = rowbase + quad * 4 + r;
                    if (ct4 < 8) {
                        int ch = 16 * ct4 + lp;
                        ws[OFF_PA + (size_t)node * 128 + ch] = acc[r] + be1[(l + 1) * 128 + ch];
                    } else {
                        int ch = 16 * (ct4 - 8) + lp;
                        pbh[(size_t)node * 128 + ch] = f2bf(acc[r]);
                    }
                }
            }
        }
    } else {
        // ---- l==2: v = h @ Wout^T (N=64: waves 0..3) + loss + 384-WG election
        const short* bwo = (const short*)(ws + OFF_BWO);
        f32x4 accv = (f32x4){0.f, 0.f, 0.f, 0.f};
        bool act = (w < 4);
        if (act) {
            #pragma unroll
            for (int s = 0; s < 4; s++) {
                int kb = s * 32 + quad * 8;
                bf16x8 af = zf;
                if (lp < 8) af = *(const bf16x8*)(hS + lp * 136 + kb);
                bf16x8 bf = *(const bf16x8*)(bwo + (size_t)(16 * w + lp) * 128 + kb);
                accv = __builtin_amdgcn_mfma_f32_16x16x32_bf16(af, bf, accv, 0, 0, 0);
            }
        }
        int sft = shiftp[0] % NN; if (sft < 0) sft += NN;
        float ep = 0.f, en = 0.f;
        if (act && quad < 2) {
            int col = 16 * w + lp;
            float bo = bout[col];
            #pragma unroll
            for (int r = 0; r < 4; r++) {
                int node = rowbase + quad * 4 + r;
                if (gmask[node] != 0) {
                    int ip = node + sft; if (ip >= NN) ip -= NN;
                    float v  = accv[r] + bo;
                    float tp = H1[(size_t)node * 64 + col] - H0[(size_t)node * 64 + col];
                    float tn = H1[(size_t)ip * 64 + col]  - H0[(size_t)ip * 64 + col];
                    float dp = v - tp, dn = v - tn;
                    ep += dp * dp;
                    en += dn * dn;
                }
            }
        }
        #pragma unroll
        for (int o = 1; o < 64; o <<= 1) {
            ep += __shfl_xor(ep, o);
            en += __shfl_xor(en, o);
        }
        if (act && lane == 0) { redE[w] = ep; redN[w] = en; }

        if (tid < 8) {
            int node = rowbase + tid;
            if (gmask[node] != 0) {
                int ip = node + sft; if (ip >= NN) ip -= NN;
                float xp = 0.f, xn = 0.f;
                #pragma unroll
                for (int d = 0; d < 3; d++) {
                    float xv  = ws[OFF_X + (size_t)node * 3 + d];
                    float tpx = X1[(size_t)node * 3 + d] - X0[(size_t)node * 3 + d];
                    float tnx = X1[(size_t)ip * 3 + d]   - X0[(size_t)ip * 3 + d];
                    xp += (xv - tpx) * (xv - tpx);
                    xn += (xv - tnx) * (xv - tnx);
                }
                atomicAdd(&sxp, xp);
                atomicAdd(&sxn, xn);
                atomicAdd(&scnt, 1.0f);
            }
        }
        __syncthreads();
        if (tid == 0) {
            float eT = redE[0] + redE[1] + redE[2] + redE[3];
            float nT = redN[0] + redN[1] + redN[2] + redN[3];
            float* acc0 = ws + OFF_ACC;
            atomicAdd(acc0 + 0, eT);
            atomicAdd(acc0 + 2, nT);
            atomicAdd(acc0 + 1, sxp);
            atomicAdd(acc0 + 3, sxn);
            atomicAdd(acc0 + 4, scnt);
            // ---- final election among the 384 l==2 WGs: write out
            __threadfence();
            unsigned o2 = atomicAdd((unsigned*)(ws + OFF_CNT) + 96, 1u);
            if (o2 == 383u) {
                __threadfence();
                float a0 = atomicAdd(acc0 + 0, 0.0f);
                float a1 = atomicAdd(acc0 + 1, 0.0f);
                float a2 = atomicAdd(acc0 + 2, 0.0f);
                float a3 = atomicAdd(acc0 + 3, 0.0f);
                float a4 = atomicAdd(acc0 + 4, 0.0f);
                float msum = a4 + 1e-8f;
                float lhp = a0 / msum, lxp = a1 / msum;
                float lhn = a2 / msum, lxn = a3 / msum;
                out[0] = lhp - 0.05f * lhn;
                out[1] = lxp - 0.05f * lxn;
                out[2] = lhp;
                out[3] = lxp;
                out[4] = lhn;
                out[5] = lxn;
            }
        }
    }
}

extern "C" void kernel_launch(void* const* d_in, const int* in_sizes, int n_in,
                              void* d_out, int out_size, void* d_ws, size_t ws_size,
                              hipStream_t stream) {
    (void)in_sizes; (void)n_in; (void)out_size; (void)ws_size;
    const float* H0   = (const float*)d_in[0];
    const float* X0   = (const float*)d_in[1];
    const float* H1   = (const float*)d_in[2];
    const float* X1   = (const float*)d_in[3];
    const float* cond = (const float*)d_in[4];
    const float* tg   = (const float*)d_in[5];
    const float* Wi1  = (const float*)d_in[6];
    const float* bi1  = (const float*)d_in[7];
    const float* Wi2  = (const float*)d_in[8];
    const float* bi2  = (const float*)d_in[9];
    const float* Wi3  = (const float*)d_in[10];
    const float* bi3  = (const float*)d_in[11];
    const float* etab = (const float*)d_in[12];
    const float* We1  = (const float*)d_in[13];
    const float* be1  = (const float*)d_in[14];
    const float* We2  = (const float*)d_in[15];
    const float* be2  = (const float*)d_in[16];
    const float* Wx   = (const float*)d_in[17];
    const float* Wh1  = (const float*)d_in[18];
    const float* bh1  = (const float*)d_in[19];
    const float* Wh2  = (const float*)d_in[20];
    const float* bh2  = (const float*)d_in[21];
    const float* Wout = (const float*)d_in[22];
    const float* bout = (const float*)d_in[23];
    const int* chain   = (const int*)d_in[25];
    const int* gmask   = (const int*)d_in[26];
    const int* lengths = (const int*)d_in[27];
    const int* shiftp  = (const int*)d_in[28];
    float* ws  = (float*)d_ws;
    float* out = (float*)d_out;

    k0_all<<<1473, 256, 0, stream>>>(etab, We1, lengths, We2, Wh1, Wh2,
                                     Wout, Wi1, Wi2, Wi3, ws);
    k1s_node_init<<<dim3(NBATCH, 6), 256, 0, stream>>>(H0, X0, H1, X1, cond, tg,
                                                       bi1, bi2, bi3, be1, gmask, ws);
    for (int l = 0; l < 3; l++) {
        k3v_edge<<<NN / KG, 384, 0, stream>>>(We1, Wx, be2, chain, l, ws);
        k4s_node_post<<<dim3(NBATCH, 12), 512, 0, stream>>>(bh1, bh2, be1, bout,
                                                            H0, X0, H1, X1, gmask, shiftp,
                                                            l, ws, out);
    }
}

// Round 6
// 356.840 us; speedup vs baseline: 1.1575x; 1.0599x over previous
//
#include <hip/hip_runtime.h>
#include <hip/hip_bf16.h>
#include <math.h>

// Problem constants
#define NBATCH 32
#define LSEQ   96
#define NN     3072
#define HID    128
#define LAT    64
#define EEMB   32

// Workspace layout (float offsets). Total ~6.35 MB.
#define OFF_H      0                          // N x 128 fp32
#define OFF_X      (OFF_H   + NN*HID)         // N x 3
#define OFF_PA     (OFF_X   + NN*3)           // N x 128 fp32 (pa + be1)
#define OFF_AGG    (OFF_PA  + NN*HID)         // N x 128
#define OFF_DX     (OFF_AGG + NN*HID)         // N x 3
#define OFF_ET     (OFF_DX  + NN*3)           // 3*2*128 fp32
#define OFF_ACC    (OFF_ET  + 768)            // 8
#define OFF_NBID   (OFF_ACC + 8)              // N int
#define OFF_CUM    (OFF_NBID + NN)            // 40 int
#define OFF_PBH    (OFF_CUM + 40)             // N x 128 bf16 (as 196608 floats)
#define OFF_BPE    (OFF_PBH + NN*HID/2)       // We2^T  bf16: 3*128*128 -> 24576 floats
#define OFF_BAB    (OFF_BPE + 24576)          // We1[0:256]^T bf16: 3*256*128 -> 49152
#define OFF_BH1    (OFF_BAB + 49152)          // Wh1^T bf16: 3*128*256 -> 49152
#define OFF_BH2    (OFF_BH1 + 49152)          // Wh2^T bf16: 3*128*128 -> 24576
#define OFF_BWO    (OFF_BH2 + 24576)          // Wout^T bf16: 64*128 -> 4096 floats
#define OFF_BWI1   (OFF_BWO + 4096)           // Wi1^T bf16: 128x320 -> 20480 floats
#define OFF_BWI2   (OFF_BWI1 + 20480)         // Wi2^T bf16: 128x128 -> 8192 floats
#define OFF_BWI3   (OFF_BWI2 + 8192)          // Wi3^T bf16: 128x128 -> 8192 floats
#define OFF_CNT    (OFF_BWI3 + 8192)          // 128 uint: [96] = final-election counter

typedef short bf16x8 __attribute__((ext_vector_type(8)));
typedef float f32x4  __attribute__((ext_vector_type(4)));

__device__ __forceinline__ short f2bf(float f) {
    unsigned u = __builtin_bit_cast(unsigned, f);
    unsigned r = (u + 0x7FFFu + ((u >> 16) & 1u)) >> 16;
    return (short)r;
}
__device__ __forceinline__ short2 f2bf2(float a, float b) {
    __hip_bfloat162 h = __float22bfloat162_rn(make_float2(a, b));
    short2 r;
    __builtin_memcpy(&r, &h, sizeof(r));
    return r;
}
__device__ __forceinline__ float bf2f(short s) {
    unsigned u = ((unsigned)(unsigned short)s) << 16;
    return __builtin_bit_cast(float, u);
}
__device__ __forceinline__ float silu(float z) {
    return z * __builtin_amdgcn_rcpf(1.0f + __expf(-z));
}

// --------------------- K0: prep + weight transposes (merged)
__global__ void k0_all(const float* __restrict__ edge_table, const float* __restrict__ We1,
                       const int* __restrict__ lengths, const float* __restrict__ We2,
                       const float* __restrict__ Wh1, const float* __restrict__ Wh2,
                       const float* __restrict__ Wout, const float* __restrict__ Wi1,
                       const float* __restrict__ Wi2, const float* __restrict__ Wi3,
                       float* __restrict__ ws) {
    int tid = threadIdx.x;
    if (blockIdx.x == 1472) {
        int* cum = (int*)(ws + OFF_CUM);
        int* nb  = (int*)(ws + OFF_NBID);
        float* et = ws + OFF_ET;
        if (tid == 0) {
            int s = 0;
            for (int b = 0; b < NBATCH; b++) { cum[b] = s; s += lengths[b]; }
            cum[NBATCH] = s;
        }
        if (tid < 8) ws[OFF_ACC + tid] = 0.0f;
        if (tid < 128) ((unsigned*)(ws + OFF_CNT))[tid] = 0u;
        __syncthreads();
        for (int i = tid; i < NN; i += blockDim.x) {
            int b = NBATCH - 1;
            for (int q = 0; q < NBATCH; q++) { if (i < cum[q + 1]) { b = q; break; } }
            nb[i] = b;
        }
        for (int idx = tid; idx < 3 * 2 * HID; idx += blockDim.x) {
            int c = idx & 127;
            int t = (idx >> 7) & 1;
            int l = idx >> 8;
            const float* w = We1 + (l * 289 + 257) * HID + c;
            const float* e = edge_table + t * EEMB;
            float s = 0.f;
            for (int k = 0; k < EEMB; k++) s += e[k] * w[k * HID];
            et[idx] = s;
        }
        return;
    }
    int idx = blockIdx.x * 256 + tid;   // 0 .. 376831
    short* bpe  = (short*)(ws + OFF_BPE);
    short* bab  = (short*)(ws + OFF_BAB);
    short* bh1  = (short*)(ws + OFF_BH1);
    short* bh2  = (short*)(ws + OFF_BH2);
    short* bwo  = (short*)(ws + OFF_BWO);
    short* bwi1 = (short*)(ws + OFF_BWI1);
    short* bwi2 = (short*)(ws + OFF_BWI2);
    short* bwi3 = (short*)(ws + OFF_BWI3);
    if (idx < 49152) {
        int k = idx & 127, n = (idx >> 7) & 127, l = idx >> 14;
        bpe[idx] = f2bf(We2[(l * 128 + k) * 128 + n]);
    } else if (idx < 147456) {
        int q = idx - 49152;
        int k = q & 127, n = (q >> 7) & 255, l = q >> 15;
        float v = (n < 128) ? We1[(l * 289 + k) * 128 + n]
                            : We1[(l * 289 + 128 + k) * 128 + (n - 128)];
        bab[q] = f2bf(v);
    } else if (idx < 245760) {
        int q = idx - 147456;
        int k = q & 255, n = (q >> 8) & 127, l = q >> 15;
        bh1[q] = f2bf(Wh1[(l * 256 + k) * 128 + n]);
    } else if (idx < 294912) {
        int q = idx - 245760;
        int k = q & 127, n = (q >> 7) & 127, l = q >> 14;
        bh2[q] = f2bf(Wh2[(l * 128 + k) * 128 + n]);
    } else if (idx < 303104) {
        int q = idx - 294912;
        int k = q & 127, n = q >> 7;          // n < 64
        bwo[q] = f2bf(Wout[k * 64 + n]);
    } else if (idx < 344064) {
        int q = idx - 303104;                  // [n<128][k<320]
        int n = q / 320, k = q - n * 320;
        bwi1[q] = f2bf(Wi1[k * 128 + n]);
    } else if (idx < 360448) {
        int q = idx - 344064;
        int k = q & 127, n = q >> 7;
        bwi2[q] = f2bf(Wi2[k * 128 + n]);
    } else if (idx < 376832) {
        int q = idx - 360448;
        int k = q & 127, n = q >> 7;
        bwi3[q] = f2bf(Wi3[k * 128 + n]);
    }
}

// ------------- K1s: init MLP row-split — grid (32, 6), 256 thr, 16 nodes/WG
__global__ void __launch_bounds__(256)
k1s_node_init(const float* __restrict__ H0, const float* __restrict__ X0,
              const float* __restrict__ H1, const float* __restrict__ X1,
              const float* __restrict__ cond, const float* __restrict__ tg,
              const float* __restrict__ bi1, const float* __restrict__ bi2,
              const float* __restrict__ bi3, const float* __restrict__ be1,
              const int* __restrict__ gmask, float* __restrict__ ws) {
    __shared__ short u1[16 * 136];
    __shared__ short u2[16 * 136];
    int rowbase = blockIdx.x * 96 + blockIdx.y * 16;
    int tid = threadIdx.x;
    int w = tid >> 6, lane = tid & 63;
    int quad = lane >> 4, lp = lane & 15;
    int nodeA = rowbase + lp;
    const int* nb = (const int*)(ws + OFF_NBID);
    float t = tg[nb[nodeA]];
    float u = (gmask[nodeA] != 0) ? t : 1.0f;

    if (tid < 48) {
        int node = rowbase + tid / 3, d = tid % 3;
        float tn = tg[nb[node]];
        float un = (gmask[node] != 0) ? tn : 1.0f;
        ws[OFF_X + (size_t)node * 3 + d] =
            (1.0f - un) * X0[(size_t)node * 3 + d] + un * X1[(size_t)node * 3 + d];
    }

    const short* bwi1 = (const short*)(ws + OFF_BWI1);
    const short* bwi2 = (const short*)(ws + OFF_BWI2);
    const short* bwi3 = (const short*)(ws + OFF_BWI3);
    const short* bab  = (const short*)(ws + OFF_BAB);   // l = 0

    // ---- GEMM1: K=320
    f32x4 acc[2];
    acc[0] = (f32x4){0.f, 0.f, 0.f, 0.f};
    acc[1] = (f32x4){0.f, 0.f, 0.f, 0.f};
    for (int s = 0; s < 10; s++) {
        int kb = s * 32 + quad * 8;
        float z[8];
        if (kb < 64) {
            const float* h0 = H0 + (size_t)nodeA * 64 + kb;
            const float* h1 = H1 + (size_t)nodeA * 64 + kb;
            #pragma unroll
            for (int e = 0; e < 8; e++) z[e] = (1.0f - u) * h0[e] + u * h1[e];
        } else if (kb < 192) {
            const float* cp = cond + (size_t)nodeA * 128 + (kb - 64);
            #pragma unroll
            for (int e = 0; e < 8; e++) z[e] = cp[e];
        } else if (kb < 256) {
            #pragma unroll
            for (int e = 0; e < 8; e++) {
                float c = (float)(kb - 192 + e);
                float fr = __expf(-9.2103403719761836f * c / 63.0f);
                z[e] = __sinf(t * fr);
            }
        } else {
            #pragma unroll
            for (int e = 0; e < 8; e++) {
                float c = (float)(kb - 256 + e);
                float fr = __expf(-9.2103403719761836f * c / 63.0f);
                z[e] = __cosf(t * fr);
            }
        }
        bf16x8 af;
        #pragma unroll
        for (int e = 0; e < 8; e += 2) {
            short2 p = f2bf2(z[e], z[e + 1]);
            af[e] = p.x; af[e + 1] = p.y;
        }
        #pragma unroll
        for (int i = 0; i < 2; i++) {
            int ct = 2 * w + i;
            bf16x8 bf = *(const bf16x8*)(bwi1 + (size_t)(16 * ct + lp) * 320 + kb);
            acc[i] = __builtin_amdgcn_mfma_f32_16x16x32_bf16(af, bf, acc[i], 0, 0, 0);
        }
    }
    #pragma unroll
    for (int i = 0; i < 2; i++) {
        int ch = 16 * (2 * w + i) + lp;
        float bb1 = bi1[ch];
        #pragma unroll
        for (int r = 0; r < 4; r++)
            u1[(quad * 4 + r) * 136 + ch] = f2bf(fmaxf(acc[i][r] + bb1, 0.0f));
    }
    __syncthreads();

    // ---- GEMM2: K=128
    acc[0] = (f32x4){0.f, 0.f, 0.f, 0.f};
    acc[1] = (f32x4){0.f, 0.f, 0.f, 0.f};
    #pragma unroll
    for (int s = 0; s < 4; s++) {
        int kb = s * 32 + quad * 8;
        bf16x8 af = *(const bf16x8*)(u1 + lp * 136 + kb);
        #pragma unroll
        for (int i = 0; i < 2; i++) {
            int ct = 2 * w + i;
            bf16x8 bf = *(const bf16x8*)(bwi2 + (size_t)(16 * ct + lp) * 128 + kb);
            acc[i] = __builtin_amdgcn_mfma_f32_16x16x32_bf16(af, bf, acc[i], 0, 0, 0);
        }
    }
    #pragma unroll
    for (int i = 0; i < 2; i++) {
        int ch = 16 * (2 * w + i) + lp;
        float bb2 = bi2[ch];
        #pragma unroll
        for (int r = 0; r < 4; r++)
            u2[(quad * 4 + r) * 136 + ch] = f2bf(fmaxf(acc[i][r] + bb2, 0.0f));
    }
    __syncthreads();

    // ---- GEMM3: K=128 -> h (no relu)
    acc[0] = (f32x4){0.f, 0.f, 0.f, 0.f};
    acc[1] = (f32x4){0.f, 0.f, 0.f, 0.f};
    #pragma unroll
    for (int s = 0; s < 4; s++) {
        int kb = s * 32 + quad * 8;
        bf16x8 af = *(const bf16x8*)(u2 + lp * 136 + kb);
        #pragma unroll
        for (int i = 0; i < 2; i++) {
            int ct = 2 * w + i;
            bf16x8 bf = *(const bf16x8*)(bwi3 + (size_t)(16 * ct + lp) * 128 + kb);
            acc[i] = __builtin_amdgcn_mfma_f32_16x16x32_bf16(af, bf, acc[i], 0, 0, 0);
        }
    }
    #pragma unroll
    for (int i = 0; i < 2; i++) {
        int ch = 16 * (2 * w + i) + lp;
        float bb3 = bi3[ch];
        #pragma unroll
        for (int r = 0; r < 4; r++) {
            int row = quad * 4 + r;
            float h = acc[i][r] + bb3;
            ws[OFF_H + (size_t)(rowbase + row) * 128 + ch] = h;
            u1[row * 136 + ch] = f2bf(h);
        }
    }
    __syncthreads();

    // ---- GEMM4: pa/pb layer 0, N=256 (ct4 = 4w..4w+3)
    f32x4 acc4[4];
    #pragma unroll
    for (int i = 0; i < 4; i++) acc4[i] = (f32x4){0.f, 0.f, 0.f, 0.f};
    #pragma unroll
    for (int s = 0; s < 4; s++) {
        int kb = s * 32 + quad * 8;
        bf16x8 af = *(const bf16x8*)(u1 + lp * 136 + kb);
        #pragma unroll
        for (int i = 0; i < 4; i++) {
            int ct4 = 4 * w + i;
            bf16x8 bf = *(const bf16x8*)(bab + (size_t)(16 * ct4 + lp) * 128 + kb);
            acc4[i] = __builtin_amdgcn_mfma_f32_16x16x32_bf16(af, bf, acc4[i], 0, 0, 0);
        }
    }
    short* pbh = (short*)(ws + OFF_PBH);
    #pragma unroll
    for (int i = 0; i < 4; i++) {
        int ct4 = 4 * w + i;
        #pragma unroll
        for (int r = 0; r < 4; r++) {
            int node = rowbase + quad * 4 + r;
            if (ct4 < 8) {
                int ch = 16 * ct4 + lp;
                ws[OFF_PA + (size_t)node * 128 + ch] = acc4[i][r] + be1[ch];
            } else {
                int ch = 16 * (ct4 - 8) + lp;
                pbh[(size_t)node * 128 + ch] = f2bf(acc4[i][r]);
            }
        }
    }
}

// -------- K3w6: edge kernel, WAVE-PER-G, zero inner barriers.
// 6 waves, wave w owns node g=i0+w and iterates all 96 columns itself
// (6 col-frags x 8 t-tiles). agg is fully in-register (butterfly shuffles),
// dX accumulated per-quad in registers -> no aggP/coefS LDS, no barriers
// after the single stage barrier; waves free-run for latency hiding.
// pb staged into LDS (stride 136 -> 2-way, free): inner loop is LDS-only.
// LDS 65.5 KB -> exactly 2 blocks/CU; grid 512 = 2/CU.
#define KG 6
#define S_BS    0        // short[2048][8] swizzled = 32768
#define S_PB    32768    // bf16 [96][136] = 26112
#define S_PE0   58880    // float[6][128] = 3072
#define S_PE1   61952    // float[6][128] = 3072
#define S_WC    65024    // float[128] = 512
#define S_XC    65536    // float[96][3] = 1152
#define S_CH    66688    // int[96] = 384  -> total 67072
__global__ void __launch_bounds__(384)
k3w_edge(const float* __restrict__ We1, const float* __restrict__ Wx,
         const float* __restrict__ be2, const int* __restrict__ chain,
         int l, float* __restrict__ ws) {
    __shared__ __align__(16) char smem[67072];
    short* bS    = (short*)(smem + S_BS);
    short* pbS   = (short*)(smem + S_PB);
    float* pe0S  = (float*)(smem + S_PE0);
    float* pe1S  = (float*)(smem + S_PE1);
    float* wcS   = (float*)(smem + S_WC);
    float* xcS   = (float*)(smem + S_XC);
    int*   chS   = (int*)  (smem + S_CH);

    int tid = threadIdx.x;
    int i0 = blockIdx.x * KG;
    int colbase = (i0 / 96) * 96;
    const float* Xc = ws + OFF_X;

    // ---- stage: We2 tile + pb tile + pe0/pe1 + wc + x cols + chain
    {
        const short* bpe = (const short*)(ws + OFF_BPE) + (size_t)l * 128 * 128;
        for (int idx = tid; idx < 2048; idx += 384) {
            int t = idx >> 8, s = (idx >> 6) & 3, ln = idx & 63;
            int lq = ln >> 4, lpp = ln & 15;
            *(bf16x8*)(bS + idx * 8) =
                *(const bf16x8*)(bpe + (size_t)(16 * t + lpp) * 128 + s * 32 + lq * 8);
        }
        const short* pbh = (const short*)(ws + OFF_PBH);
        for (int idx = tid; idx < 1536; idx += 384) {
            int j = idx >> 4, kc = (idx & 15) * 8;
            *(bf16x8*)(pbS + j * 136 + kc) =
                *(const bf16x8*)(pbh + (size_t)(colbase + j) * 128 + kc);
        }
        if (tid < 128) {
            float et0 = ws[OFF_ET + l * 256 + tid];
            float et1 = ws[OFF_ET + l * 256 + 128 + tid];
            #pragma unroll
            for (int g = 0; g < KG; g++) {
                float pav = ws[OFF_PA + (size_t)(i0 + g) * 128 + tid];
                pe0S[g * 128 + tid] = pav + et0;
                pe1S[g * 128 + tid] = pav + et1;
            }
            wcS[tid] = We1[(l * 289 + 256) * 128 + tid];
        }
        if (tid < 288) xcS[tid] = Xc[(size_t)colbase * 3 + tid];
        if (tid < 96)  chS[tid] = chain[colbase + tid];
    }

    int w = tid >> 6, lane = tid & 63;
    int quad = lane >> 4, lp = lane & 15;
    // per-lane epilogue constants (global/L2, issued before the barrier)
    float be2r[8], wxr[8];
    #pragma unroll
    for (int t = 0; t < 8; t++) {
        int ch = 16 * t + lp;
        be2r[t] = be2[l * 128 + ch];
        wxr[t]  = Wx[l * 128 + ch];
    }
    __syncthreads();

    // ---- wave w owns g = i0 + w; NO barriers from here on
    int g  = i0 + w;
    int gl = (i0 - colbase) + w;
    float xg0 = xcS[gl * 3 + 0], xg1 = xcS[gl * 3 + 1], xg2 = xcS[gl * 3 + 2];
    int cig = chS[gl];
    const float* pe0w = pe0S + w * 128;
    const float* pe1w = pe1S + w * 128;

    float agReg[8];
    #pragma unroll
    for (int t = 0; t < 8; t++) agReg[t] = 0.f;
    float dxa0 = 0.f, dxa1 = 0.f, dxa2 = 0.f;

    #pragma unroll
    for (int f = 0; f < 6; f++) {
        int j = 16 * f + lp;                       // lane's column (A row)
        float dx = xg0 - xcS[j * 3 + 0];
        float dy = xg1 - xcS[j * 3 + 1];
        float dz = xg2 - xcS[j * 3 + 2];
        float d2 = dx * dx + dy * dy + dz * dz;
        const float* peB = (chS[j] != cig) ? pe1w : pe0w;

        bf16x8 af[4];
        #pragma unroll
        for (int s = 0; s < 4; s++) {
            int kb = s * 32 + quad * 8;
            bf16x8 pb = *(const bf16x8*)(pbS + j * 136 + kb);
            float4 w0 = *(const float4*)(wcS + kb);
            float4 w1 = *(const float4*)(wcS + kb + 4);
            float wcv[8] = {w0.x, w0.y, w0.z, w0.w, w1.x, w1.y, w1.z, w1.w};
            float4 p0 = *(const float4*)(peB + kb);
            float4 p1 = *(const float4*)(peB + kb + 4);
            float pev[8] = {p0.x, p0.y, p0.z, p0.w, p1.x, p1.y, p1.z, p1.w};
            float z[8];
            #pragma unroll
            for (int e = 0; e < 8; e++)
                z[e] = silu(pev[e] + bf2f(pb[e]) + d2 * wcv[e]);
            #pragma unroll
            for (int e = 0; e < 8; e += 2) {
                short2 p = f2bf2(z[e], z[e + 1]);
                af[s][e] = p.x; af[s][e + 1] = p.y;
            }
        }

        f32x4 acc[8];
        #pragma unroll
        for (int t = 0; t < 8; t++) acc[t] = (f32x4){0.f, 0.f, 0.f, 0.f};
        #pragma unroll
        for (int t = 0; t < 8; t++) {
            #pragma unroll
            for (int s = 0; s < 4; s++) {
                bf16x8 bf = *(const bf16x8*)(bS + ((t * 4 + s) * 64 + lane) * 8);
                acc[t] = __builtin_amdgcn_mfma_f32_16x16x32_bf16(af[s], bf, acc[t], 0, 0, 0);
            }
        }

        // epilogue for this f: m2[j=16f+quad*4+r][ch=16t+lp]
        float cp[4] = {0.f, 0.f, 0.f, 0.f};
        #pragma unroll
        for (int t = 0; t < 8; t++) {
            float ag = 0.f;
            #pragma unroll
            for (int r = 0; r < 4; r++) {
                float m2 = silu(acc[t][r] + be2r[t]);
                ag += m2;
                cp[r] += m2 * wxr[t];
            }
            ag += __shfl_xor(ag, 16);
            ag += __shfl_xor(ag, 32);
            agReg[t] += ag;
        }
        #pragma unroll
        for (int r = 0; r < 4; r++) {
            float v = cp[r];
            v += __shfl_xor(v, 1);
            v += __shfl_xor(v, 2);
            v += __shfl_xor(v, 4);
            v += __shfl_xor(v, 8);
            if (lp == 0) {
                int jj = 16 * f + quad * 4 + r;
                dxa0 += (xg0 - xcS[jj * 3 + 0]) * v;
                dxa1 += (xg1 - xcS[jj * 3 + 1]) * v;
                dxa2 += (xg2 - xcS[jj * 3 + 2]) * v;
            }
        }
    }

    // ---- writeback: agg from registers; dX via quad butterfly
    if (lane < 16) {
        #pragma unroll
        for (int t = 0; t < 8; t++)
            ws[OFF_AGG + (size_t)g * 128 + 16 * t + lane] = agReg[t];
    }
    dxa0 += __shfl_xor(dxa0, 16); dxa0 += __shfl_xor(dxa0, 32);
    dxa1 += __shfl_xor(dxa1, 16); dxa1 += __shfl_xor(dxa1, 32);
    dxa2 += __shfl_xor(dxa2, 16); dxa2 += __shfl_xor(dxa2, 32);
    if (lane == 0) {
        ws[OFF_DX + (size_t)g * 3 + 0] = dxa0;
        ws[OFF_DX + (size_t)g * 3 + 1] = dxa1;
        ws[OFF_DX + (size_t)g * 3 + 2] = dxa2;
    }
}

// ----- K4s: node update row-split — grid (32, 6), 256 thr, 16 nodes/WG
// (R2's best-measured version, reverted from R5's k4s8 experiment)
__global__ void __launch_bounds__(256)
k4s_node_post(const float* __restrict__ bh1, const float* __restrict__ bh2,
              const float* __restrict__ be1, const float* __restrict__ bout,
              const float* __restrict__ H0, const float* __restrict__ X0,
              const float* __restrict__ H1, const float* __restrict__ X1,
              const int* __restrict__ gmask, const int* __restrict__ shiftp,
              int l, float* __restrict__ ws, float* __restrict__ out) {
    __shared__ short uS[16 * 136];
    __shared__ short hS[16 * 136];
    __shared__ float redE[4], redN[4];
    __shared__ float sxp, sxn, scnt;
    int rowbase = blockIdx.x * 96 + blockIdx.y * 16;
    int tid = threadIdx.x;
    int w = tid >> 6, lane = tid & 63;
    int quad = lane >> 4, lp = lane & 15;
    int nodeA = rowbase + lp;
    const short* b1 = (const short*)(ws + OFF_BH1) + (size_t)l * 128 * 256;
    const short* b2 = (const short*)(ws + OFF_BH2) + (size_t)l * 128 * 128;

    if (tid == 0) { sxp = 0.f; sxn = 0.f; scnt = 0.f; }
    if (tid < 48) {
        int node = rowbase + tid / 3, d = tid % 3;
        ws[OFF_X + (size_t)node * 3 + d] += ws[OFF_DX + (size_t)node * 3 + d];
    }

    // ---- GEMM1: [h|agg] K=256 -> u (silu); ct = 2w+i
    f32x4 acc[2];
    acc[0] = (f32x4){0.f, 0.f, 0.f, 0.f};
    acc[1] = (f32x4){0.f, 0.f, 0.f, 0.f};
    #pragma unroll
    for (int s = 0; s < 8; s++) {
        int kb = s * 32 + quad * 8;
        const float* src = (kb < 128) ? (ws + OFF_H + (size_t)nodeA * 128 + kb)
                                      : (ws + OFF_AGG + (size_t)nodeA * 128 + (kb - 128));
        bf16x8 af;
        #pragma unroll
        for (int e = 0; e < 8; e += 2) {
            short2 p = f2bf2(src[e], src[e + 1]);
            af[e] = p.x; af[e + 1] = p.y;
        }
        #pragma unroll
        for (int i = 0; i < 2; i++) {
            int ct = 2 * w + i;
            bf16x8 bf = *(const bf16x8*)(b1 + (size_t)(16 * ct + lp) * 256 + kb);
            acc[i] = __builtin_amdgcn_mfma_f32_16x16x32_bf16(af, bf, acc[i], 0, 0, 0);
        }
    }
    #pragma unroll
    for (int i = 0; i < 2; i++) {
        int ch = 16 * (2 * w + i) + lp;
        float bb1 = bh1[l * 128 + ch];
        #pragma unroll
        for (int r = 0; r < 4; r++)
            uS[(quad * 4 + r) * 136 + ch] = f2bf(silu(acc[i][r] + bb1));
    }
    __syncthreads();

    // ---- GEMM2: u @ Wh2 -> h += ; hS = bf16(h)
    acc[0] = (f32x4){0.f, 0.f, 0.f, 0.f};
    acc[1] = (f32x4){0.f, 0.f, 0.f, 0.f};
    #pragma unroll
    for (int s = 0; s < 4; s++) {
        int kb = s * 32 + quad * 8;
        bf16x8 af = *(const bf16x8*)(uS + lp * 136 + kb);
        #pragma unroll
        for (int i = 0; i < 2; i++) {
            int ct = 2 * w + i;
            bf16x8 bf = *(const bf16x8*)(b2 + (size_t)(16 * ct + lp) * 128 + kb);
            acc[i] = __builtin_amdgcn_mfma_f32_16x16x32_bf16(af, bf, acc[i], 0, 0, 0);
        }
    }
    #pragma unroll
    for (int i = 0; i < 2; i++) {
        int ch = 16 * (2 * w + i) + lp;
        float bb2 = bh2[l * 128 + ch];
        #pragma unroll
        for (int r = 0; r < 4; r++) {
            int row = quad * 4 + r;
            size_t off = OFF_H + (size_t)(rowbase + row) * 128 + ch;
            float h = ws[off] + acc[i][r] + bb2;
            ws[off] = h;
            hS[row * 136 + ch] = f2bf(h);
        }
    }
    __syncthreads();

    if (l < 2) {
        // ---- GEMM3: pa/pb for layer l+1, N=256 (ct4 = 4w+i)
        const short* bab = (const short*)(ws + OFF_BAB) + (size_t)(l + 1) * 256 * 128;
        f32x4 acc4[4];
        #pragma unroll
        for (int i = 0; i < 4; i++) acc4[i] = (f32x4){0.f, 0.f, 0.f, 0.f};
        #pragma unroll
        for (int s = 0; s < 4; s++) {
            int kb = s * 32 + quad * 8;
            bf16x8 af = *(const bf16x8*)(hS + lp * 136 + kb);
            #pragma unroll
            for (int i = 0; i < 4; i++) {
                int ct4 = 4 * w + i;
                bf16x8 bf = *(const bf16x8*)(bab + (size_t)(16 * ct4 + lp) * 128 + kb);
                acc4[i] = __builtin_amdgcn_mfma_f32_16x16x32_bf16(af, bf, acc4[i], 0, 0, 0);
            }
        }
        short* pbh = (short*)(ws + OFF_PBH);
        #pragma unroll
        for (int i = 0; i < 4; i++) {
            int ct4 = 4 * w + i;
            #pragma unroll
            for (int r = 0; r < 4; r++) {
                int node = rowbase + quad * 4 + r;
                if (ct4 < 8) {
                    int ch = 16 * ct4 + lp;
                    ws[OFF_PA + (size_t)node * 128 + ch] = acc4[i][r] + be1[(l + 1) * 128 + ch];
                } else {
                    int ch = 16 * (ct4 - 8) + lp;
                    pbh[(size_t)node * 128 + ch] = f2bf(acc4[i][r]);
                }
            }
        }
    } else {
        // ---- GEMM3: v = h @ Wout^T (N=64, ct=w) + loss reduction + final out
        const short* bwo = (const short*)(ws + OFF_BWO);
        f32x4 accv = (f32x4){0.f, 0.f, 0.f, 0.f};
        #pragma unroll
        for (int s = 0; s < 4; s++) {
            int kb = s * 32 + quad * 8;
            bf16x8 af = *(const bf16x8*)(hS + lp * 136 + kb);
            bf16x8 bf = *(const bf16x8*)(bwo + (size_t)(16 * w + lp) * 128 + kb);
            accv = __builtin_amdgcn_mfma_f32_16x16x32_bf16(af, bf, accv, 0, 0, 0);
        }
        int s = shiftp[0] % NN; if (s < 0) s += NN;
        int col = 16 * w + lp;
        float bo = bout[col];
        float ep = 0.f, en = 0.f;
        #pragma unroll
        for (int r = 0; r < 4; r++) {
            int row = rowbase + quad * 4 + r;
            if (gmask[row] != 0) {
                int ip = row + s; if (ip >= NN) ip -= NN;
                float v  = accv[r] + bo;
                float tp = H1[(size_t)row * 64 + col] - H0[(size_t)row * 64 + col];
                float tn = H1[(size_t)ip * 64 + col]  - H0[(size_t)ip * 64 + col];
                float dp = v - tp, dn = v - tn;
                ep += dp * dp;
                en += dn * dn;
            }
        }
        #pragma unroll
        for (int o = 1; o < 64; o <<= 1) {
            ep += __shfl_xor(ep, o);
            en += __shfl_xor(en, o);
        }
        if (lane == 0) { redE[w] = ep; redN[w] = en; }

        if (tid < 16) {
            int node = rowbase + tid;
            if (gmask[node] != 0) {
                int ip = node + s; if (ip >= NN) ip -= NN;
                float xp = 0.f, xn = 0.f;
                #pragma unroll
                for (int d = 0; d < 3; d++) {
                    float xv  = ws[OFF_X + (size_t)node * 3 + d];
                    float tpx = X1[(size_t)node * 3 + d] - X0[(size_t)node * 3 + d];
                    float tnx = X1[(size_t)ip * 3 + d]   - X0[(size_t)ip * 3 + d];
                    xp += (xv - tpx) * (xv - tpx);
                    xn += (xv - tnx) * (xv - tnx);
                }
                atomicAdd(&sxp, xp);
                atomicAdd(&sxn, xn);
                atomicAdd(&scnt, 1.0f);
            }
        }
        __syncthreads();
        if (tid == 0) {
            float eT = redE[0] + redE[1] + redE[2] + redE[3];
            float nT = redN[0] + redN[1] + redN[2] + redN[3];
            float* acc0 = ws + OFF_ACC;
            atomicAdd(acc0 + 0, eT);
            atomicAdd(acc0 + 2, nT);
            atomicAdd(acc0 + 1, sxp);
            atomicAdd(acc0 + 3, sxn);
            atomicAdd(acc0 + 4, scnt);
            // ---- final election among the 192 l==2 WGs: write out
            __threadfence();
            unsigned o2 = atomicAdd((unsigned*)(ws + OFF_CNT) + 96, 1u);
            if (o2 == 191u) {
                __threadfence();
                float a0 = atomicAdd(acc0 + 0, 0.0f);
                float a1 = atomicAdd(acc0 + 1, 0.0f);
                float a2 = atomicAdd(acc0 + 2, 0.0f);
                float a3 = atomicAdd(acc0 + 3, 0.0f);
                float a4 = atomicAdd(acc0 + 4, 0.0f);
                float msum = a4 + 1e-8f;
                float lhp = a0 / msum, lxp = a1 / msum;
                float lhn = a2 / msum, lxn = a3 / msum;
                out[0] = lhp - 0.05f * lhn;
                out[1] = lxp - 0.05f * lxn;
                out[2] = lhp;
                out[3] = lxp;
                out[4] = lhn;
                out[5] = lxn;
            }
        }
    }
}

extern "C" void kernel_launch(void* const* d_in, const int* in_sizes, int n_in,
                              void* d_out, int out_size, void* d_ws, size_t ws_size,
                              hipStream_t stream) {
    (void)in_sizes; (void)n_in; (void)out_size; (void)ws_size;
    const float* H0   = (const float*)d_in[0];
    const float* X0   = (const float*)d_in[1];
    const float* H1   = (const float*)d_in[2];
    const float* X1   = (const float*)d_in[3];
    const float* cond = (const float*)d_in[4];
    const float* tg   = (const float*)d_in[5];
    const float* Wi1  = (const float*)d_in[6];
    const float* bi1  = (const float*)d_in[7];
    const float* Wi2  = (const float*)d_in[8];
    const float* bi2  = (const float*)d_in[9];
    const float* Wi3  = (const float*)d_in[10];
    const float* bi3  = (const float*)d_in[11];
    const float* etab = (const float*)d_in[12];
    const float* We1  = (const float*)d_in[13];
    const float* be1  = (const float*)d_in[14];
    const float* We2  = (const float*)d_in[15];
    const float* be2  = (const float*)d_in[16];
    const float* Wx   = (const float*)d_in[17];
    const float* Wh1  = (const float*)d_in[18];
    const float* bh1  = (const float*)d_in[19];
    const float* Wh2  = (const float*)d_in[20];
    const float* bh2  = (const float*)d_in[21];
    const float* Wout = (const float*)d_in[22];
    const float* bout = (const float*)d_in[23];
    const int* chain   = (const int*)d_in[25];
    const int* gmask   = (const int*)d_in[26];
    const int* lengths = (const int*)d_in[27];
    const int* shiftp  = (const int*)d_in[28];
    float* ws  = (float*)d_ws;
    float* out = (float*)d_out;

    k0_all<<<1473, 256, 0, stream>>>(etab, We1, lengths, We2, Wh1, Wh2,
                                     Wout, Wi1, Wi2, Wi3, ws);
    k1s_node_init<<<dim3(NBATCH, 6), 256, 0, stream>>>(H0, X0, H1, X1, cond, tg,
                                                       bi1, bi2, bi3, be1, gmask, ws);
    for (int l = 0; l < 3; l++) {
        k3w_edge<<<NN / KG, 384, 0, stream>>>(We1, Wx, be2, chain, l, ws);
        k4s_node_post<<<dim3(NBATCH, 6), 256, 0, stream>>>(bh1, bh2, be1, bout,
                                                           H0, X0, H1, X1, gmask, shiftp,
                                                           l, ws, out);
    }
}